// Round 16
// baseline (70.261 us; speedup 1.0000x reference)
//
#include <hip/hip_runtime.h>
#include <math.h>

#define B_  2048
#define T_  200
#define D_  64
#define H1_ 80
#define H2_ 40

#define WSTR 104   // W2T row stride (bf16): 208 B rows -> ~2-way banks
#define HSTR 104   // h1 row stride (bf16); cols 80..95 zero pad

// d_ws layout (bytes):
#define WS_A    0        // A[h][f]  bf16 [80][64]
#define WS_C    10240    // C[h][f]  bf16 [80][64]
#define WS_W2T  20480    // W2Tp[g][h] bf16 [48][104]
#define WS_ACT  30464    // W1acT[h][f] f32 [80][64]

typedef __bf16 bf16x8 __attribute__((ext_vector_type(8)));
typedef float  f32x4  __attribute__((ext_vector_type(4)));

__device__ __forceinline__ float sigmoidf_(float x) {
    return __builtin_amdgcn_rcpf(1.0f + __expf(-x));
}

// ---------- prep: block-invariant weight transforms ----------
__global__ __launch_bounds__(256)
void prep_kernel(const float* __restrict__ W1, const float* __restrict__ W2,
                 void* __restrict__ ws)
{
    __bf16* A    = (__bf16*)((char*)ws + WS_A);
    __bf16* C    = (__bf16*)((char*)ws + WS_C);
    __bf16* W2Tp = (__bf16*)((char*)ws + WS_W2T);
    float*  acT  = (float*)((char*)ws + WS_ACT);
    const int e0 = blockIdx.x * 256 + threadIdx.x;

    for (int e = e0; e < H1_ * D_; e += 2048) {
        int h = e >> 6, f = e & 63;
        float wb = W1[(64  + f) * H1_ + h];
        float wc = W1[(128 + f) * H1_ + h];
        float wd = W1[(192 + f) * H1_ + h];
        float wa = W1[f * H1_ + h];
        A[e]   = (__bf16)(wb - wc);
        C[e]   = (__bf16)wd;
        acT[e] = wa + wc;
    }
    for (int e = e0; e < 48 * WSTR; e += 2048) {
        int g = e / WSTR, h = e - g * WSTR;
        W2Tp[e] = (g < H2_ && h < H1_) ? (__bf16)W2[h * H2_ + g] : (__bf16)0.0f;
    }
}

// ---------- main: one batch per wave @ 3 waves/SIMD; W2T block-shared in LDS ----------
__global__ __launch_bounds__(256, 3)
void attn_din16(const float* __restrict__ query,
                const float* __restrict__ key,
                const int*   __restrict__ mask,
                const float* __restrict__ b1,
                const float* __restrict__ b2,
                const float* __restrict__ W3,
                const float* __restrict__ b3,
                const void*  __restrict__ ws,
                float* __restrict__ out)
{
    __shared__ __align__(16) __bf16 s_W2T[48 * WSTR];    //  9984 B (block-shared, batch-indep)
    __shared__ __align__(16) __bf16 s_h1[4][16 * HSTR];  // 13312 B (per-wave)
    __shared__ __align__(16) float  s_q[4][D_];          //  1024 B
    __shared__ float s_base[4][H1_];                      //  1280 B
    __shared__ float s_sc16[4][16];                       //   256 B
    __shared__ float s_part[4][D_];                       //  1024 B
    // ~26.9 KB -> 3 blocks/CU (reg-capped), 12 waves/CU

    const int tid  = threadIdx.x;
    const int lane = tid & 63;
    const int w    = tid >> 6;
    const int c16  = lane & 15;
    const int g16  = lane >> 4;
    const int b    = blockIdx.x * 4 + w;       // wave-private batch

    const int   mv     = mask[b];
    const int   ntiles = (mv + 15) >> 4;
    const float b3v    = b3[0];
    const float* kb = key + (size_t)b * T_ * D_;

    const __bf16* wsA   = (const __bf16*)((const char*)ws + WS_A);
    const __bf16* wsC   = (const __bf16*)((const char*)ws + WS_C);
    const uint4*  wsW2T = (const uint4*) ((const char*)ws + WS_W2T);
    const float*  wsacT = (const float*) ((const char*)ws + WS_ACT);

    // ---- issue q + tile-0 key loads early ----
    float qv = query[b * D_ + lane];
    float4 u0, u1, u2, u3;
    {
        const float* kr = kb + (size_t)c16 * D_ + g16 * 8;  // tile 0 always live (mv>=1)
        u0 = *(const float4*)(kr);
        u1 = *(const float4*)(kr + 4);
        u2 = *(const float4*)(kr + 32);
        u3 = *(const float4*)(kr + 36);
    }

    // ---- stage W2T to block-shared LDS (624 16B chunks over 256 threads) ----
    {
        uint4* dst = (uint4*)s_W2T;
        #pragma unroll
        for (int i = 0; i < 3; ++i) {
            int e = tid + 256 * i;
            if (e < 624) dst[e] = wsW2T[e];
        }
    }
    s_q[w][lane] = qv;

    float b2c[3], w3c[3];
    #pragma unroll
    for (int nt = 0; nt < 3; ++nt) {
        int g = nt * 16 + c16;
        b2c[nt] = (g < H2_) ? b2[g] : 0.0f;
        w3c[nt] = (g < H2_) ? W3[g] : 0.0f;
    }

    // ---- base[h] = b1[h] + q.(W1a+W1c) (own-wave LDS q; lgkm-only wait) ----
    {
        float a0 = b1[lane], a1 = 0.0f, a2 = 0.0f, a3 = 0.0f;
        const f32x4* row = (const f32x4*)&wsacT[lane * D_];
        #pragma unroll
        for (int f4 = 0; f4 < 16; ++f4) {
            f32x4 v  = row[f4];
            f32x4 q4 = *(const f32x4*)&s_q[w][f4 * 4];
            a0 = fmaf(q4[0], v[0], a0);
            a1 = fmaf(q4[1], v[1], a1);
            a2 = fmaf(q4[2], v[2], a2);
            a3 = fmaf(q4[3], v[3], a3);
        }
        s_base[w][lane] = (a0 + a1) + (a2 + a3);
    }
    if (lane < 16) {
        int h = 64 + lane;
        float a0 = b1[h], a1 = 0.0f, a2 = 0.0f, a3 = 0.0f;
        const f32x4* row = (const f32x4*)&wsacT[h * D_];
        #pragma unroll
        for (int f4 = 0; f4 < 16; ++f4) {
            f32x4 v  = row[f4];
            f32x4 q4 = *(const f32x4*)&s_q[w][f4 * 4];
            a0 = fmaf(q4[0], v[0], a0);
            a1 = fmaf(q4[1], v[1], a1);
            a2 = fmaf(q4[2], v[2], a2);
            a3 = fmaf(q4[3], v[3], a3);
        }
        s_base[w][h] = (a0 + a1) + (a2 + a3);
    }

    // ---- bv[5][2] B-fragments in registers (V = A + q*C at MFMA B positions) ----
    bf16x8 bv[5][2];
    #pragma unroll
    for (int nt = 0; nt < 5; ++nt)
        #pragma unroll
        for (int ks = 0; ks < 2; ++ks) {
            int off = (nt * 16 + c16) * D_ + ks * 32 + g16 * 8;
            bf16x8 a8 = *(const bf16x8*)&wsA[off];
            bf16x8 c8 = *(const bf16x8*)&wsC[off];
            f32x4 q0 = *(const f32x4*)&s_q[w][ks * 32 + g16 * 8];
            f32x4 q1 = *(const f32x4*)&s_q[w][ks * 32 + g16 * 8 + 4];
            bf16x8 v8;
            v8[0] = (__bf16)((float)a8[0] + q0[0] * (float)c8[0]);
            v8[1] = (__bf16)((float)a8[1] + q0[1] * (float)c8[1]);
            v8[2] = (__bf16)((float)a8[2] + q0[2] * (float)c8[2]);
            v8[3] = (__bf16)((float)a8[3] + q0[3] * (float)c8[3]);
            v8[4] = (__bf16)((float)a8[4] + q1[0] * (float)c8[4]);
            v8[5] = (__bf16)((float)a8[5] + q1[1] * (float)c8[5]);
            v8[6] = (__bf16)((float)a8[6] + q1[2] * (float)c8[6]);
            v8[7] = (__bf16)((float)a8[7] + q1[3] * (float)c8[7]);
            bv[nt][ks] = v8;
        }

    // ---- zero h1 pad cols 80..95 (own-wave tile, once) ----
    {
        int row = lane & 15, c0 = 80 + (lane >> 4) * 4;
        *(uint2*)&s_h1[w][row * HSTR + c0] = make_uint2(0u, 0u);
    }

    float base_c[5];
    #pragma unroll
    for (int nt = 0; nt < 5; ++nt) base_c[nt] = s_base[w][nt * 16 + c16];
    __bf16* myh = &s_h1[w][0];

    __syncthreads();   // the only barrier: W2T staging visible to all waves

    // ---- flash state ----
    float o00,o01,o02,o03,o04,o05,o06,o07,o08,o09,o10,o11,o12,o13,o14,o15;
    o00=o01=o02=o03=o04=o05=o06=o07=o08=o09=o10=o11=o12=o13=o14=o15=0.0f;
    float m_run = -1e30f, l_run = 0.0f;

    // ---------------- main loop: all own-batch tiles, barrier-free ----------------
    for (int tt = 0; tt < ntiles; ++tt) {
        bf16x8 af0, af1;
        af0[0] = (__bf16)u0.x; af0[1] = (__bf16)u0.y; af0[2] = (__bf16)u0.z; af0[3] = (__bf16)u0.w;
        af0[4] = (__bf16)u1.x; af0[5] = (__bf16)u1.y; af0[6] = (__bf16)u1.z; af0[7] = (__bf16)u1.w;
        af1[0] = (__bf16)u2.x; af1[1] = (__bf16)u2.y; af1[2] = (__bf16)u2.z; af1[3] = (__bf16)u2.w;
        af1[4] = (__bf16)u3.x; af1[5] = (__bf16)u3.y; af1[6] = (__bf16)u3.z; af1[7] = (__bf16)u3.w;

        // T14 prefetch next tile (overwrites u; af carries current keys)
        if (tt + 1 < ntiles) {
            int tr = (tt + 1) * 16 + c16;
            const float* kr = kb + (size_t)((tr < T_) ? tr : (T_ - 1)) * D_ + g16 * 8;
            u0 = *(const float4*)(kr);
            u1 = *(const float4*)(kr + 4);
            u2 = *(const float4*)(kr + 32);
            u3 = *(const float4*)(kr + 36);
        }

        // layer 1 -> sigmoid -> h1 (own-wave LDS transpose); B from registers
        #pragma unroll
        for (int nt = 0; nt < 5; ++nt) {
            float bb = base_c[nt];
            f32x4 c = { bb, bb, bb, bb };
            c = __builtin_amdgcn_mfma_f32_16x16x32_bf16(af0, bv[nt][0], c, 0, 0, 0);
            c = __builtin_amdgcn_mfma_f32_16x16x32_bf16(af1, bv[nt][1], c, 0, 0, 0);
            #pragma unroll
            for (int r = 0; r < 4; ++r)
                myh[(g16 * 4 + r) * HSTR + nt * 16 + c16] = (__bf16)sigmoidf_(c[r]);
        }

        // layer 2 (k=0..95 incl. zero pad); B from block-shared LDS
        bf16x8 a2_0 = *(const bf16x8*)&myh[c16 * HSTR + g16 * 8];
        bf16x8 a2_1 = *(const bf16x8*)&myh[c16 * HSTR + 32 + g16 * 8];
        bf16x8 a2_2 = *(const bf16x8*)&myh[c16 * HSTR + 64 + g16 * 8];
        f32x4 acc2[3];
        #pragma unroll
        for (int nt = 0; nt < 3; ++nt) {
            float bb = b2c[nt];
            f32x4 c = { bb, bb, bb, bb };
            bf16x8 w0 = *(const bf16x8*)&s_W2T[(nt * 16 + c16) * WSTR + g16 * 8];
            bf16x8 w1 = *(const bf16x8*)&s_W2T[(nt * 16 + c16) * WSTR + 32 + g16 * 8];
            bf16x8 w2 = *(const bf16x8*)&s_W2T[(nt * 16 + c16) * WSTR + 64 + g16 * 8];
            c = __builtin_amdgcn_mfma_f32_16x16x32_bf16(a2_0, w0, c, 0, 0, 0);
            c = __builtin_amdgcn_mfma_f32_16x16x32_bf16(a2_1, w1, c, 0, 0, 0);
            c = __builtin_amdgcn_mfma_f32_16x16x32_bf16(a2_2, w2, c, 0, 0, 0);
            acc2[nt] = c;
        }

        // layer 3 + masked score -> s_sc16 (own wave)
        const int tb = tt * 16;
        #pragma unroll
        for (int r = 0; r < 4; ++r) {
            float partial = sigmoidf_(acc2[0][r]) * w3c[0]
                          + sigmoidf_(acc2[1][r]) * w3c[1]
                          + sigmoidf_(acc2[2][r]) * w3c[2];
            partial += __shfl_xor(partial, 1);
            partial += __shfl_xor(partial, 2);
            partial += __shfl_xor(partial, 4);
            partial += __shfl_xor(partial, 8);
            if (c16 == 0) {
                int t = tb + g16 * 4 + r;
                s_sc16[w][g16 * 4 + r] = (t < mv) ? (partial + b3v) * 0.125f : -1e30f;
            }
        }

        // online softmax + o-update (key values from af = current tile's bf16 frags)
        float s = s_sc16[w][c16];
        float tm = s;
        tm = fmaxf(tm, __shfl_xor(tm, 1));
        tm = fmaxf(tm, __shfl_xor(tm, 2));
        tm = fmaxf(tm, __shfl_xor(tm, 4));
        tm = fmaxf(tm, __shfl_xor(tm, 8));
        float m_new = fmaxf(m_run, tm);
        float alpha = __expf(m_run - m_new);
        float p = __expf(s - m_new);
        float psum = p;
        psum += __shfl_xor(psum, 1);
        psum += __shfl_xor(psum, 2);
        psum += __shfl_xor(psum, 4);
        psum += __shfl_xor(psum, 8);
        l_run = l_run * alpha + psum;
        o00 = fmaf(p, (float)af0[0], o00 * alpha);  o01 = fmaf(p, (float)af0[1], o01 * alpha);
        o02 = fmaf(p, (float)af0[2], o02 * alpha);  o03 = fmaf(p, (float)af0[3], o03 * alpha);
        o04 = fmaf(p, (float)af0[4], o04 * alpha);  o05 = fmaf(p, (float)af0[5], o05 * alpha);
        o06 = fmaf(p, (float)af0[6], o06 * alpha);  o07 = fmaf(p, (float)af0[7], o07 * alpha);
        o08 = fmaf(p, (float)af1[0], o08 * alpha);  o09 = fmaf(p, (float)af1[1], o09 * alpha);
        o10 = fmaf(p, (float)af1[2], o10 * alpha);  o11 = fmaf(p, (float)af1[3], o11 * alpha);
        o12 = fmaf(p, (float)af1[4], o12 * alpha);  o13 = fmaf(p, (float)af1[5], o13 * alpha);
        o14 = fmaf(p, (float)af1[6], o14 * alpha);  o15 = fmaf(p, (float)af1[7], o15 * alpha);
        m_run = m_new;
    }

    // ---------------- finalize: reduce o over c16 lanes, normalize, store ----------------
    #define ORED(X) X += __shfl_xor(X,1); X += __shfl_xor(X,2); X += __shfl_xor(X,4); X += __shfl_xor(X,8);
    ORED(o00) ORED(o01) ORED(o02) ORED(o03) ORED(o04) ORED(o05) ORED(o06) ORED(o07)
    ORED(o08) ORED(o09) ORED(o10) ORED(o11) ORED(o12) ORED(o13) ORED(o14) ORED(o15)
    #undef ORED
    float inv_total = __builtin_amdgcn_rcpf(l_run);
    if (c16 == 0) {
        float* sp = &s_part[w][0];
        sp[g16 * 8 + 0] = o00;  sp[g16 * 8 + 1] = o01;
        sp[g16 * 8 + 2] = o02;  sp[g16 * 8 + 3] = o03;
        sp[g16 * 8 + 4] = o04;  sp[g16 * 8 + 5] = o05;
        sp[g16 * 8 + 6] = o06;  sp[g16 * 8 + 7] = o07;
        sp[32 + g16 * 8 + 0] = o08;  sp[32 + g16 * 8 + 1] = o09;
        sp[32 + g16 * 8 + 2] = o10;  sp[32 + g16 * 8 + 3] = o11;
        sp[32 + g16 * 8 + 4] = o12;  sp[32 + g16 * 8 + 5] = o13;
        sp[32 + g16 * 8 + 6] = o14;  sp[32 + g16 * 8 + 7] = o15;
    }
    asm volatile("s_waitcnt lgkmcnt(0)" ::: "memory");
    out[b * D_ + lane] = s_part[w][lane] * inv_total;
}

extern "C" void kernel_launch(void* const* d_in, const int* in_sizes, int n_in,
                              void* d_out, int out_size, void* d_ws, size_t ws_size,
                              hipStream_t stream)
{
    const float* query = (const float*)d_in[0];
    const float* key   = (const float*)d_in[1];
    const int*   mask  = (const int*)  d_in[2];
    const float* W1    = (const float*)d_in[3];
    const float* b1    = (const float*)d_in[4];
    const float* W2    = (const float*)d_in[5];
    const float* b2    = (const float*)d_in[6];
    const float* W3    = (const float*)d_in[7];
    const float* b3    = (const float*)d_in[8];
    float* out = (float*)d_out;

    prep_kernel<<<8, 256, 0, stream>>>(W1, W2, d_ws);
    attn_din16<<<512, 256, 0, stream>>>(query, key, mask, b1, b2, W3, b3, d_ws, out);
}

// Round 17
// 45.181 us; speedup vs baseline: 1.5551x; 1.5551x over previous
//
#include <hip/hip_runtime.h>
#include <math.h>

#define B_  2048
#define T_  200
#define D_  64
#define H1_ 80
#define H2_ 40

#define WSTR 104   // ws W2T row stride (bf16)
#define HSTR 104   // h1 row stride (bf16); cols 80..95 zero pad; 32 rows/wave

// d_ws layout (bytes):
#define WS_A    0        // A[h][f]  bf16 [80][64]
#define WS_C    10240    // C[h][f]  bf16 [80][64]
#define WS_W2T  20480    // W2Tp[g][h] bf16 [48][104]
#define WS_ACT  30464    // W1acT[h][f] f32 [80][64]

typedef __bf16 bf16x8 __attribute__((ext_vector_type(8)));
typedef float  f32x4  __attribute__((ext_vector_type(4)));

__device__ __forceinline__ float sigmoidf_(float x) {
    return __builtin_amdgcn_rcpf(1.0f + __expf(-x));
}

// ---------- prep: block-invariant weight transforms ----------
__global__ __launch_bounds__(256)
void prep_kernel(const float* __restrict__ W1, const float* __restrict__ W2,
                 void* __restrict__ ws)
{
    __bf16* A    = (__bf16*)((char*)ws + WS_A);
    __bf16* C    = (__bf16*)((char*)ws + WS_C);
    __bf16* W2Tp = (__bf16*)((char*)ws + WS_W2T);
    float*  acT  = (float*)((char*)ws + WS_ACT);
    const int e0 = blockIdx.x * 256 + threadIdx.x;

    for (int e = e0; e < H1_ * D_; e += 2048) {
        int h = e >> 6, f = e & 63;
        float wb = W1[(64  + f) * H1_ + h];
        float wc = W1[(128 + f) * H1_ + h];
        float wd = W1[(192 + f) * H1_ + h];
        float wa = W1[f * H1_ + h];
        A[e]   = (__bf16)(wb - wc);
        C[e]   = (__bf16)wd;
        acT[e] = wa + wc;
    }
    for (int e = e0; e < 48 * WSTR; e += 2048) {
        int g = e / WSTR, h = e - g * WSTR;
        W2Tp[e] = (g < H2_ && h < H1_) ? (__bf16)W2[h * H2_ + g] : (__bf16)0.0f;
    }
}

// ---------- main: one batch per wave, 32-row pairs, fixed-m softmax, zero barriers ----------
__global__ __launch_bounds__(256, 2)
void attn_din17(const float* __restrict__ query,
                const float* __restrict__ key,
                const int*   __restrict__ mask,
                const float* __restrict__ b1,
                const float* __restrict__ b2,
                const float* __restrict__ W3,
                const float* __restrict__ b3,
                const void*  __restrict__ ws,
                float* __restrict__ out)
{
    __shared__ __align__(16) __bf16 s_h1[4][32 * HSTR];    // 26624 B (32 rows/wave)
    __shared__ __align__(16) float  s_q[4][D_];
    __shared__ float s_base[4][H1_];
    __shared__ float s_part[4][D_];
    // ~29.5 KB

    const int tid  = threadIdx.x;
    const int lane = tid & 63;
    const int w    = tid >> 6;
    const int c16  = lane & 15;
    const int g16  = lane >> 4;
    const int b    = blockIdx.x * 4 + w;

    const int   mv     = mask[b];
    const int   npairs = (mv + 31) >> 5;       // ceil(mv/32)
    const float b3v    = b3[0];
    const float* kb = key + (size_t)b * T_ * D_;

    const __bf16* wsA   = (const __bf16*)((const char*)ws + WS_A);
    const __bf16* wsC   = (const __bf16*)((const char*)ws + WS_C);
    const __bf16* wsW2T = (const __bf16*)((const char*)ws + WS_W2T);
    const float*  wsacT = (const float*) ((const char*)ws + WS_ACT);

    // ---- q + pair-0 key loads issued early ----
    float qv = query[b * D_ + lane];
    float4 uA0, uA1, uA2, uA3, uB0, uB1, uB2, uB3;
    {
        const float* krA = kb + (size_t)c16 * D_ + g16 * 8;          // rows 0..15
        const float* krB = kb + (size_t)(16 + c16) * D_ + g16 * 8;   // rows 16..31 (<200)
        uA0 = *(const float4*)(krA);      uA1 = *(const float4*)(krA + 4);
        uA2 = *(const float4*)(krA + 32); uA3 = *(const float4*)(krA + 36);
        uB0 = *(const float4*)(krB);      uB1 = *(const float4*)(krB + 4);
        uB2 = *(const float4*)(krB + 32); uB3 = *(const float4*)(krB + 36);
    }
    s_q[w][lane] = qv;

    // ---- W2T fragments into registers ----
    bf16x8 bw[3][3];
    #pragma unroll
    for (int nt = 0; nt < 3; ++nt)
        #pragma unroll
        for (int ks = 0; ks < 3; ++ks)
            bw[nt][ks] = *(const bf16x8*)&wsW2T[(nt * 16 + c16) * WSTR + ks * 32 + g16 * 8];

    float b2c[3], w3c[3];
    #pragma unroll
    for (int nt = 0; nt < 3; ++nt) {
        int g = nt * 16 + c16;
        b2c[nt] = (g < H2_) ? b2[g] : 0.0f;
        w3c[nt] = (g < H2_) ? W3[g] : 0.0f;
    }

    // ---- base[h] ----
    {
        float a0 = b1[lane], a1 = 0.0f, a2 = 0.0f, a3 = 0.0f;
        const f32x4* row = (const f32x4*)&wsacT[lane * D_];
        #pragma unroll
        for (int f4 = 0; f4 < 16; ++f4) {
            f32x4 v  = row[f4];
            f32x4 q4 = *(const f32x4*)&s_q[w][f4 * 4];
            a0 = fmaf(q4[0], v[0], a0);
            a1 = fmaf(q4[1], v[1], a1);
            a2 = fmaf(q4[2], v[2], a2);
            a3 = fmaf(q4[3], v[3], a3);
        }
        s_base[w][lane] = (a0 + a1) + (a2 + a3);
    }
    if (lane < 16) {
        int h = 64 + lane;
        float a0 = b1[h], a1 = 0.0f, a2 = 0.0f, a3 = 0.0f;
        const f32x4* row = (const f32x4*)&wsacT[h * D_];
        #pragma unroll
        for (int f4 = 0; f4 < 16; ++f4) {
            f32x4 v  = row[f4];
            f32x4 q4 = *(const f32x4*)&s_q[w][f4 * 4];
            a0 = fmaf(q4[0], v[0], a0);
            a1 = fmaf(q4[1], v[1], a1);
            a2 = fmaf(q4[2], v[2], a2);
            a3 = fmaf(q4[3], v[3], a3);
        }
        s_base[w][h] = (a0 + a1) + (a2 + a3);
    }

    // ---- V B-fragments in registers ----
    bf16x8 bv[5][2];
    #pragma unroll
    for (int nt = 0; nt < 5; ++nt)
        #pragma unroll
        for (int ks = 0; ks < 2; ++ks) {
            int off = (nt * 16 + c16) * D_ + ks * 32 + g16 * 8;
            bf16x8 a8 = *(const bf16x8*)&wsA[off];
            bf16x8 c8 = *(const bf16x8*)&wsC[off];
            f32x4 q0 = *(const f32x4*)&s_q[w][ks * 32 + g16 * 8];
            f32x4 q1 = *(const f32x4*)&s_q[w][ks * 32 + g16 * 8 + 4];
            bf16x8 v8;
            v8[0] = (__bf16)((float)a8[0] + q0[0] * (float)c8[0]);
            v8[1] = (__bf16)((float)a8[1] + q0[1] * (float)c8[1]);
            v8[2] = (__bf16)((float)a8[2] + q0[2] * (float)c8[2]);
            v8[3] = (__bf16)((float)a8[3] + q0[3] * (float)c8[3]);
            v8[4] = (__bf16)((float)a8[4] + q1[0] * (float)c8[4]);
            v8[5] = (__bf16)((float)a8[5] + q1[1] * (float)c8[5]);
            v8[6] = (__bf16)((float)a8[6] + q1[2] * (float)c8[6]);
            v8[7] = (__bf16)((float)a8[7] + q1[3] * (float)c8[7]);
            bv[nt][ks] = v8;
        }

    // ---- zero h1 pad cols 80..95 for all 32 rows (once) ----
    {
        int row = lane & 31, c0 = 80 + (lane >> 5) * 8;
        *(uint4*)&s_h1[w][row * HSTR + c0] = make_uint4(0u, 0u, 0u, 0u);
    }

    float base_c[5];
    #pragma unroll
    for (int nt = 0; nt < 5; ++nt) base_c[nt] = s_base[w][nt * 16 + c16];
    __bf16* myh = &s_h1[w][0];

    // ---- accumulators (fixed-m softmax: pure sums, no rescale) ----
    float o00,o01,o02,o03,o04,o05,o06,o07,o08,o09,o10,o11,o12,o13,o14,o15;
    o00=o01=o02=o03=o04=o05=o06=o07=o08=o09=o10=o11=o12=o13=o14=o15=0.0f;
    float l_run = 0.0f;

    // ---------------- main loop: 32 rows (two 16-row m-tiles) per iteration ----------------
    for (int pp = 0; pp < npairs; ++pp) {
        bf16x8 afA0, afA1, afB0, afB1;
        afA0[0]=(__bf16)uA0.x; afA0[1]=(__bf16)uA0.y; afA0[2]=(__bf16)uA0.z; afA0[3]=(__bf16)uA0.w;
        afA0[4]=(__bf16)uA1.x; afA0[5]=(__bf16)uA1.y; afA0[6]=(__bf16)uA1.z; afA0[7]=(__bf16)uA1.w;
        afA1[0]=(__bf16)uA2.x; afA1[1]=(__bf16)uA2.y; afA1[2]=(__bf16)uA2.z; afA1[3]=(__bf16)uA2.w;
        afA1[4]=(__bf16)uA3.x; afA1[5]=(__bf16)uA3.y; afA1[6]=(__bf16)uA3.z; afA1[7]=(__bf16)uA3.w;
        afB0[0]=(__bf16)uB0.x; afB0[1]=(__bf16)uB0.y; afB0[2]=(__bf16)uB0.z; afB0[3]=(__bf16)uB0.w;
        afB0[4]=(__bf16)uB1.x; afB0[5]=(__bf16)uB1.y; afB0[6]=(__bf16)uB1.z; afB0[7]=(__bf16)uB1.w;
        afB1[0]=(__bf16)uB2.x; afB1[1]=(__bf16)uB2.y; afB1[2]=(__bf16)uB2.z; afB1[3]=(__bf16)uB2.w;
        afB1[4]=(__bf16)uB3.x; afB1[5]=(__bf16)uB3.y; afB1[6]=(__bf16)uB3.z; afB1[7]=(__bf16)uB3.w;

        // T14 prefetch next pair (clamped rows)
        if (pp + 1 < npairs) {
            int trA = (pp + 1) * 32 + c16;
            int trB = trA + 16;
            const float* krA = kb + (size_t)((trA < T_) ? trA : (T_ - 1)) * D_ + g16 * 8;
            const float* krB = kb + (size_t)((trB < T_) ? trB : (T_ - 1)) * D_ + g16 * 8;
            uA0 = *(const float4*)(krA);      uA1 = *(const float4*)(krA + 4);
            uA2 = *(const float4*)(krA + 32); uA3 = *(const float4*)(krA + 36);
            uB0 = *(const float4*)(krB);      uB1 = *(const float4*)(krB + 4);
            uB2 = *(const float4*)(krB + 32); uB3 = *(const float4*)(krB + 36);
        }

        // layer 1 (A,B) -> sigmoid -> h1 rows 0..15 / 16..31
        #pragma unroll
        for (int nt = 0; nt < 5; ++nt) {
            float bb = base_c[nt];
            f32x4 cA = { bb, bb, bb, bb };
            cA = __builtin_amdgcn_mfma_f32_16x16x32_bf16(afA0, bv[nt][0], cA, 0, 0, 0);
            cA = __builtin_amdgcn_mfma_f32_16x16x32_bf16(afA1, bv[nt][1], cA, 0, 0, 0);
            f32x4 cB = { bb, bb, bb, bb };
            cB = __builtin_amdgcn_mfma_f32_16x16x32_bf16(afB0, bv[nt][0], cB, 0, 0, 0);
            cB = __builtin_amdgcn_mfma_f32_16x16x32_bf16(afB1, bv[nt][1], cB, 0, 0, 0);
            #pragma unroll
            for (int r = 0; r < 4; ++r) {
                myh[(g16 * 4 + r) * HSTR + nt * 16 + c16]      = (__bf16)sigmoidf_(cA[r]);
                myh[(16 + g16 * 4 + r) * HSTR + nt * 16 + c16] = (__bf16)sigmoidf_(cB[r]);
            }
        }

        // layer 2 (A and B)
        bf16x8 a2A0 = *(const bf16x8*)&myh[c16 * HSTR + g16 * 8];
        bf16x8 a2A1 = *(const bf16x8*)&myh[c16 * HSTR + 32 + g16 * 8];
        bf16x8 a2A2 = *(const bf16x8*)&myh[c16 * HSTR + 64 + g16 * 8];
        bf16x8 a2B0 = *(const bf16x8*)&myh[(16 + c16) * HSTR + g16 * 8];
        bf16x8 a2B1 = *(const bf16x8*)&myh[(16 + c16) * HSTR + 32 + g16 * 8];
        bf16x8 a2B2 = *(const bf16x8*)&myh[(16 + c16) * HSTR + 64 + g16 * 8];
        f32x4 acc2A[3], acc2B[3];
        #pragma unroll
        for (int nt = 0; nt < 3; ++nt) {
            float bb = b2c[nt];
            f32x4 cA = { bb, bb, bb, bb };
            cA = __builtin_amdgcn_mfma_f32_16x16x32_bf16(a2A0, bw[nt][0], cA, 0, 0, 0);
            cA = __builtin_amdgcn_mfma_f32_16x16x32_bf16(a2A1, bw[nt][1], cA, 0, 0, 0);
            cA = __builtin_amdgcn_mfma_f32_16x16x32_bf16(a2A2, bw[nt][2], cA, 0, 0, 0);
            acc2A[nt] = cA;
            f32x4 cB = { bb, bb, bb, bb };
            cB = __builtin_amdgcn_mfma_f32_16x16x32_bf16(a2B0, bw[nt][0], cB, 0, 0, 0);
            cB = __builtin_amdgcn_mfma_f32_16x16x32_bf16(a2B1, bw[nt][1], cB, 0, 0, 0);
            cB = __builtin_amdgcn_mfma_f32_16x16x32_bf16(a2B2, bw[nt][2], cB, 0, 0, 0);
            acc2B[nt] = cB;
        }

        // layer 3: 8 butterfly chains; every lane of group g16 ends with row (g16*4+r)'s sum
        float redA[4], redB[4];
        #pragma unroll
        for (int r = 0; r < 4; ++r) {
            float pA = sigmoidf_(acc2A[0][r]) * w3c[0]
                     + sigmoidf_(acc2A[1][r]) * w3c[1]
                     + sigmoidf_(acc2A[2][r]) * w3c[2];
            float pB = sigmoidf_(acc2B[0][r]) * w3c[0]
                     + sigmoidf_(acc2B[1][r]) * w3c[1]
                     + sigmoidf_(acc2B[2][r]) * w3c[2];
            pA += __shfl_xor(pA, 1);  pB += __shfl_xor(pB, 1);
            pA += __shfl_xor(pA, 2);  pB += __shfl_xor(pB, 2);
            pA += __shfl_xor(pA, 4);  pB += __shfl_xor(pB, 4);
            pA += __shfl_xor(pA, 8);  pB += __shfl_xor(pB, 8);
            redA[r] = pA;  redB[r] = pB;
        }

        // redistribute: lane (g16,c16) needs row c16's score = redX[c16&3] of group (c16>>2)
        const int srcLane = ((c16 >> 2) << 4) | c16;
        float sA = 0.0f, sB = 0.0f;
        #pragma unroll
        for (int r = 0; r < 4; ++r) {
            float tA = __shfl(redA[r], srcLane);
            float tB = __shfl(redB[r], srcLane);
            if ((c16 & 3) == r) { sA = tA; sB = tB; }
        }

        // fixed-m softmax: p = exp(score) directly (|score| bounded ~1 by weight norms)
        const int tb = pp * 32;
        int tA_ = tb + c16, tB_ = tb + 16 + c16;
        float pA = (tA_ < mv) ? __expf((sA + b3v) * 0.125f) : 0.0f;
        float pB = (tB_ < mv) ? __expf((sB + b3v) * 0.125f) : 0.0f;

        float psum = pA + pB;
        psum += __shfl_xor(psum, 1);
        psum += __shfl_xor(psum, 2);
        psum += __shfl_xor(psum, 4);
        psum += __shfl_xor(psum, 8);
        l_run += psum;

        o00 = fmaf(pB, (float)afB0[0], fmaf(pA, (float)afA0[0], o00));
        o01 = fmaf(pB, (float)afB0[1], fmaf(pA, (float)afA0[1], o01));
        o02 = fmaf(pB, (float)afB0[2], fmaf(pA, (float)afA0[2], o02));
        o03 = fmaf(pB, (float)afB0[3], fmaf(pA, (float)afA0[3], o03));
        o04 = fmaf(pB, (float)afB0[4], fmaf(pA, (float)afA0[4], o04));
        o05 = fmaf(pB, (float)afB0[5], fmaf(pA, (float)afA0[5], o05));
        o06 = fmaf(pB, (float)afB0[6], fmaf(pA, (float)afA0[6], o06));
        o07 = fmaf(pB, (float)afB0[7], fmaf(pA, (float)afA0[7], o07));
        o08 = fmaf(pB, (float)afB1[0], fmaf(pA, (float)afA1[0], o08));
        o09 = fmaf(pB, (float)afB1[1], fmaf(pA, (float)afA1[1], o09));
        o10 = fmaf(pB, (float)afB1[2], fmaf(pA, (float)afA1[2], o10));
        o11 = fmaf(pB, (float)afB1[3], fmaf(pA, (float)afA1[3], o11));
        o12 = fmaf(pB, (float)afB1[4], fmaf(pA, (float)afA1[4], o12));
        o13 = fmaf(pB, (float)afB1[5], fmaf(pA, (float)afA1[5], o13));
        o14 = fmaf(pB, (float)afB1[6], fmaf(pA, (float)afA1[6], o14));
        o15 = fmaf(pB, (float)afB1[7], fmaf(pA, (float)afA1[7], o15));
    }

    // ---------------- finalize ----------------
    #define ORED(X) X += __shfl_xor(X,1); X += __shfl_xor(X,2); X += __shfl_xor(X,4); X += __shfl_xor(X,8);
    ORED(o00) ORED(o01) ORED(o02) ORED(o03) ORED(o04) ORED(o05) ORED(o06) ORED(o07)
    ORED(o08) ORED(o09) ORED(o10) ORED(o11) ORED(o12) ORED(o13) ORED(o14) ORED(o15)
    #undef ORED
    float inv_total = __builtin_amdgcn_rcpf(l_run);
    if (c16 == 0) {
        float* sp = &s_part[w][0];
        sp[g16 * 8 + 0] = o00;  sp[g16 * 8 + 1] = o01;
        sp[g16 * 8 + 2] = o02;  sp[g16 * 8 + 3] = o03;
        sp[g16 * 8 + 4] = o04;  sp[g16 * 8 + 5] = o05;
        sp[g16 * 8 + 6] = o06;  sp[g16 * 8 + 7] = o07;
        sp[32 + g16 * 8 + 0] = o08;  sp[32 + g16 * 8 + 1] = o09;
        sp[32 + g16 * 8 + 2] = o10;  sp[32 + g16 * 8 + 3] = o11;
        sp[32 + g16 * 8 + 4] = o12;  sp[32 + g16 * 8 + 5] = o13;
        sp[32 + g16 * 8 + 6] = o14;  sp[32 + g16 * 8 + 7] = o15;
    }
    asm volatile("s_waitcnt lgkmcnt(0)" ::: "memory");
    out[b * D_ + lane] = s_part[w][lane] * inv_total;
}

extern "C" void kernel_launch(void* const* d_in, const int* in_sizes, int n_in,
                              void* d_out, int out_size, void* d_ws, size_t ws_size,
                              hipStream_t stream)
{
    const float* query = (const float*)d_in[0];
    const float* key   = (const float*)d_in[1];
    const int*   mask  = (const int*)  d_in[2];
    const float* W1    = (const float*)d_in[3];
    const float* b1    = (const float*)d_in[4];
    const float* W2    = (const float*)d_in[5];
    const float* b2    = (const float*)d_in[6];
    const float* W3    = (const float*)d_in[7];
    const float* b3    = (const float*)d_in[8];
    float* out = (float*)d_out;

    prep_kernel<<<8, 256, 0, stream>>>(W1, W2, d_ws);
    attn_din17<<<512, 256, 0, stream>>>(query, key, mask, b1, b2, W3, b3, d_ws, out);
}

// Round 18
// 43.744 us; speedup vs baseline: 1.6062x; 1.0329x over previous
//
#include <hip/hip_runtime.h>
#include <math.h>

#define B_  2048
#define T_  200
#define D_  64
#define H1_ 80
#define H2_ 40

#define WSTR 104   // ws W2T row stride (bf16)

// d_ws layout (bytes):
#define WS_A    0        // A[h][f]  bf16 [80][64]
#define WS_C    10240    // C[h][f]  bf16 [80][64]
#define WS_W2T  20480    // W2Tp[g][h] bf16 [48][104]
#define WS_ACT  30464    // W1acT[h][f] f32 [80][64]

typedef __bf16 bf16x8 __attribute__((ext_vector_type(8)));
typedef float  f32x4  __attribute__((ext_vector_type(4)));

__device__ __forceinline__ float sigmoidf_(float x) {
    return __builtin_amdgcn_rcpf(1.0f + __expf(-x));
}
__device__ __forceinline__ unsigned pk2_(float a, float b) {
    __bf16 x = (__bf16)a, y = (__bf16)b;
    unsigned short ux = __builtin_bit_cast(unsigned short, x);
    unsigned short uy = __builtin_bit_cast(unsigned short, y);
    return (unsigned)ux | ((unsigned)uy << 16);
}

// ---------- prep: block-invariant weight transforms ----------
__global__ __launch_bounds__(256)
void prep_kernel(const float* __restrict__ W1, const float* __restrict__ W2,
                 void* __restrict__ ws)
{
    __bf16* A    = (__bf16*)((char*)ws + WS_A);
    __bf16* C    = (__bf16*)((char*)ws + WS_C);
    __bf16* W2Tp = (__bf16*)((char*)ws + WS_W2T);
    float*  acT  = (float*)((char*)ws + WS_ACT);
    const int e0 = blockIdx.x * 256 + threadIdx.x;

    for (int e = e0; e < H1_ * D_; e += 2048) {
        int h = e >> 6, f = e & 63;
        float wb = W1[(64  + f) * H1_ + h];
        float wc = W1[(128 + f) * H1_ + h];
        float wd = W1[(192 + f) * H1_ + h];
        float wa = W1[f * H1_ + h];
        A[e]   = (__bf16)(wb - wc);
        C[e]   = (__bf16)wd;
        acT[e] = wa + wc;
    }
    for (int e = e0; e < 48 * WSTR; e += 2048) {
        int g = e / WSTR, h = e - g * WSTR;
        W2Tp[e] = (g < H2_ && h < H1_) ? (__bf16)W2[h * H2_ + g] : (__bf16)0.0f;
    }
}

// ---------- main: one batch per wave, swapped-operand MFMAs, LDS-free main loop ----------
__global__ __launch_bounds__(256, 2)
void attn_din18(const float* __restrict__ query,
                const float* __restrict__ key,
                const int*   __restrict__ mask,
                const float* __restrict__ b1,
                const float* __restrict__ b2,
                const float* __restrict__ W3,
                const float* __restrict__ b3,
                const void*  __restrict__ ws,
                float* __restrict__ out)
{
    __shared__ __align__(16) float s_q[4][D_];
    __shared__ float s_base[4][H1_];
    __shared__ float s_part[4][D_];
    // ~3.3 KB

    const int tid  = threadIdx.x;
    const int lane = tid & 63;
    const int w    = tid >> 6;
    const int c16  = lane & 15;
    const int g16  = lane >> 4;
    const int b    = blockIdx.x * 4 + w;

    const int   mv     = mask[b];
    const int   npairs = (mv + 31) >> 5;
    const float b3v    = b3[0];
    const float* kb = key + (size_t)b * T_ * D_;

    const __bf16* wsA   = (const __bf16*)((const char*)ws + WS_A);
    const __bf16* wsC   = (const __bf16*)((const char*)ws + WS_C);
    const __bf16* wsW2T = (const __bf16*)((const char*)ws + WS_W2T);
    const float*  wsacT = (const float*) ((const char*)ws + WS_ACT);

    // ---- q + pair-0 key loads issued early ----
    float qv = query[b * D_ + lane];
    float4 uA0, uA1, uA2, uA3, uB0, uB1, uB2, uB3;
    {
        const float* krA = kb + (size_t)c16 * D_ + g16 * 8;
        const float* krB = kb + (size_t)(16 + c16) * D_ + g16 * 8;
        uA0 = *(const float4*)(krA);      uA1 = *(const float4*)(krA + 4);
        uA2 = *(const float4*)(krA + 32); uA3 = *(const float4*)(krA + 36);
        uB0 = *(const float4*)(krB);      uB1 = *(const float4*)(krB + 4);
        uB2 = *(const float4*)(krB + 32); uB3 = *(const float4*)(krB + 36);
    }
    s_q[w][lane] = qv;

    // ---- W2T A-fragments (same addresses as before; now the MFMA A operand) ----
    bf16x8 bw[3][3];
    #pragma unroll
    for (int nt = 0; nt < 3; ++nt)
        #pragma unroll
        for (int ks = 0; ks < 3; ++ks)
            bw[nt][ks] = *(const bf16x8*)&wsW2T[(nt * 16 + c16) * WSTR + ks * 32 + g16 * 8];

    // ---- per-lane bias/weight rows for swapped outputs: index g = 16*nt2 + g16*4 + r ----
    float b2c[3][4], w3c[3][4];
    #pragma unroll
    for (int nt = 0; nt < 3; ++nt)
        #pragma unroll
        for (int r = 0; r < 4; ++r) {
            int g = nt * 16 + g16 * 4 + r;
            b2c[nt][r] = (g < H2_) ? b2[g] : 0.0f;
            w3c[nt][r] = (g < H2_) ? W3[g] : 0.0f;
        }

    // ---- base[h] into LDS ----
    {
        float a0 = b1[lane], a1 = 0.0f, a2 = 0.0f, a3 = 0.0f;
        const f32x4* row = (const f32x4*)&wsacT[lane * D_];
        #pragma unroll
        for (int f4 = 0; f4 < 16; ++f4) {
            f32x4 v  = row[f4];
            f32x4 q4 = *(const f32x4*)&s_q[w][f4 * 4];
            a0 = fmaf(q4[0], v[0], a0);
            a1 = fmaf(q4[1], v[1], a1);
            a2 = fmaf(q4[2], v[2], a2);
            a3 = fmaf(q4[3], v[3], a3);
        }
        s_base[w][lane] = (a0 + a1) + (a2 + a3);
    }
    if (lane < 16) {
        int h = 64 + lane;
        float a0 = b1[h], a1 = 0.0f, a2 = 0.0f, a3 = 0.0f;
        const f32x4* row = (const f32x4*)&wsacT[h * D_];
        #pragma unroll
        for (int f4 = 0; f4 < 16; ++f4) {
            f32x4 v  = row[f4];
            f32x4 q4 = *(const f32x4*)&s_q[w][f4 * 4];
            a0 = fmaf(q4[0], v[0], a0);
            a1 = fmaf(q4[1], v[1], a1);
            a2 = fmaf(q4[2], v[2], a2);
            a3 = fmaf(q4[3], v[3], a3);
        }
        s_base[w][h] = (a0 + a1) + (a2 + a3);
    }

    // ---- V A-fragments (same addresses as before; now the MFMA A operand) ----
    bf16x8 bv[5][2];
    #pragma unroll
    for (int mt = 0; mt < 5; ++mt)
        #pragma unroll
        for (int ks = 0; ks < 2; ++ks) {
            int off = (mt * 16 + c16) * D_ + ks * 32 + g16 * 8;
            bf16x8 a8 = *(const bf16x8*)&wsA[off];
            bf16x8 c8 = *(const bf16x8*)&wsC[off];
            f32x4 q0 = *(const f32x4*)&s_q[w][ks * 32 + g16 * 8];
            f32x4 q1 = *(const f32x4*)&s_q[w][ks * 32 + g16 * 8 + 4];
            bf16x8 v8;
            v8[0] = (__bf16)((float)a8[0] + q0[0] * (float)c8[0]);
            v8[1] = (__bf16)((float)a8[1] + q0[1] * (float)c8[1]);
            v8[2] = (__bf16)((float)a8[2] + q0[2] * (float)c8[2]);
            v8[3] = (__bf16)((float)a8[3] + q0[3] * (float)c8[3]);
            v8[4] = (__bf16)((float)a8[4] + q1[0] * (float)c8[4]);
            v8[5] = (__bf16)((float)a8[5] + q1[1] * (float)c8[5]);
            v8[6] = (__bf16)((float)a8[6] + q1[2] * (float)c8[6]);
            v8[7] = (__bf16)((float)a8[7] + q1[3] * (float)c8[7]);
            bv[mt][ks] = v8;
        }

    // ---- per-lane base rows: h = 16*mt + g16*4 + r ----
    float base_c[5][4];
    #pragma unroll
    for (int mt = 0; mt < 5; ++mt)
        #pragma unroll
        for (int r = 0; r < 4; ++r)
            base_c[mt][r] = s_base[w][16 * mt + g16 * 4 + r];

    // ---- shfl-assembly constants ----
    const int  L0 = ((g16 & 1) << 5) + c16;   // source lane for j=0..3
    const int  L1 = L0 + 16;                  // source lane for j=4..7
    const bool hi = (g16 >= 2);               // selects mt = 2ks+1 vs 2ks

    // ---- accumulators (fixed-m softmax) ----
    float o00,o01,o02,o03,o04,o05,o06,o07,o08,o09,o10,o11,o12,o13,o14,o15;
    o00=o01=o02=o03=o04=o05=o06=o07=o08=o09=o10=o11=o12=o13=o14=o15=0.0f;
    float l_run = 0.0f;

    // ---------------- main loop: 32 rows per iteration, LDS-free ----------------
    for (int pp = 0; pp < npairs; ++pp) {
        // key B-fragments (same loads as ever; lane c16 = row tb+c16)
        bf16x8 afA0, afA1, afB0, afB1;
        afA0[0]=(__bf16)uA0.x; afA0[1]=(__bf16)uA0.y; afA0[2]=(__bf16)uA0.z; afA0[3]=(__bf16)uA0.w;
        afA0[4]=(__bf16)uA1.x; afA0[5]=(__bf16)uA1.y; afA0[6]=(__bf16)uA1.z; afA0[7]=(__bf16)uA1.w;
        afA1[0]=(__bf16)uA2.x; afA1[1]=(__bf16)uA2.y; afA1[2]=(__bf16)uA2.z; afA1[3]=(__bf16)uA2.w;
        afA1[4]=(__bf16)uA3.x; afA1[5]=(__bf16)uA3.y; afA1[6]=(__bf16)uA3.z; afA1[7]=(__bf16)uA3.w;
        afB0[0]=(__bf16)uB0.x; afB0[1]=(__bf16)uB0.y; afB0[2]=(__bf16)uB0.z; afB0[3]=(__bf16)uB0.w;
        afB0[4]=(__bf16)uB1.x; afB0[5]=(__bf16)uB1.y; afB0[6]=(__bf16)uB1.z; afB0[7]=(__bf16)uB1.w;
        afB1[0]=(__bf16)uB2.x; afB1[1]=(__bf16)uB2.y; afB1[2]=(__bf16)uB2.z; afB1[3]=(__bf16)uB2.w;
        afB1[4]=(__bf16)uB3.x; afB1[5]=(__bf16)uB3.y; afB1[6]=(__bf16)uB3.z; afB1[7]=(__bf16)uB3.w;

        // T14 prefetch next pair
        if (pp + 1 < npairs) {
            int trA = (pp + 1) * 32 + c16;
            int trB = trA + 16;
            const float* krA = kb + (size_t)((trA < T_) ? trA : (T_ - 1)) * D_ + g16 * 8;
            const float* krB = kb + (size_t)((trB < T_) ? trB : (T_ - 1)) * D_ + g16 * 8;
            uA0 = *(const float4*)(krA);      uA1 = *(const float4*)(krA + 4);
            uA2 = *(const float4*)(krA + 32); uA3 = *(const float4*)(krA + 36);
            uB0 = *(const float4*)(krB);      uB1 = *(const float4*)(krB + 4);
            uB2 = *(const float4*)(krB + 32); uB3 = *(const float4*)(krB + 36);
        }

        // layer 1 swapped: D[h=16mt+g16*4+r][t=c16]; sigmoid -> packed bf16 pairs
        unsigned pkA[5][2], pkB[5][2];
        #pragma unroll
        for (int mt = 0; mt < 5; ++mt) {
            f32x4 cA = { base_c[mt][0], base_c[mt][1], base_c[mt][2], base_c[mt][3] };
            cA = __builtin_amdgcn_mfma_f32_16x16x32_bf16(bv[mt][0], afA0, cA, 0, 0, 0);
            cA = __builtin_amdgcn_mfma_f32_16x16x32_bf16(bv[mt][1], afA1, cA, 0, 0, 0);
            f32x4 cB = { base_c[mt][0], base_c[mt][1], base_c[mt][2], base_c[mt][3] };
            cB = __builtin_amdgcn_mfma_f32_16x16x32_bf16(bv[mt][0], afB0, cB, 0, 0, 0);
            cB = __builtin_amdgcn_mfma_f32_16x16x32_bf16(bv[mt][1], afB1, cB, 0, 0, 0);
            pkA[mt][0] = pk2_(sigmoidf_(cA[0]), sigmoidf_(cA[1]));
            pkA[mt][1] = pk2_(sigmoidf_(cA[2]), sigmoidf_(cA[3]));
            pkB[mt][0] = pk2_(sigmoidf_(cB[0]), sigmoidf_(cB[1]));
            pkB[mt][1] = pk2_(sigmoidf_(cB[2]), sigmoidf_(cB[3]));
        }

        // B-frag assembly + layer 2 + layer 3, per sub-tile (A then B; acc2 reused)
        float sA, sB;
        #pragma unroll
        for (int sub = 0; sub < 2; ++sub) {
            // assemble h1^T B-frags from pk via column-local shfls
            unsigned w00,w01,w02,w03, w10,w11,w12,w13, w20,w21,w22,w23;
            {
                #define PKX(m,i) (sub ? pkB[m][i] : pkA[m][i])
                unsigned a,bq;
                a = __shfl(PKX(0,0), L0); bq = __shfl(PKX(1,0), L0); w00 = hi ? bq : a;
                a = __shfl(PKX(0,1), L0); bq = __shfl(PKX(1,1), L0); w01 = hi ? bq : a;
                a = __shfl(PKX(0,0), L1); bq = __shfl(PKX(1,0), L1); w02 = hi ? bq : a;
                a = __shfl(PKX(0,1), L1); bq = __shfl(PKX(1,1), L1); w03 = hi ? bq : a;
                a = __shfl(PKX(2,0), L0); bq = __shfl(PKX(3,0), L0); w10 = hi ? bq : a;
                a = __shfl(PKX(2,1), L0); bq = __shfl(PKX(3,1), L0); w11 = hi ? bq : a;
                a = __shfl(PKX(2,0), L1); bq = __shfl(PKX(3,0), L1); w12 = hi ? bq : a;
                a = __shfl(PKX(2,1), L1); bq = __shfl(PKX(3,1), L1); w13 = hi ? bq : a;
                a = __shfl(PKX(4,0), L0);                            w20 = hi ? 0u : a;
                a = __shfl(PKX(4,1), L0);                            w21 = hi ? 0u : a;
                a = __shfl(PKX(4,0), L1);                            w22 = hi ? 0u : a;
                a = __shfl(PKX(4,1), L1);                            w23 = hi ? 0u : a;
                #undef PKX
            }
            union { unsigned u[4]; bf16x8 v; } cv0, cv1, cv2;
            cv0.u[0]=w00; cv0.u[1]=w01; cv0.u[2]=w02; cv0.u[3]=w03;
            cv1.u[0]=w10; cv1.u[1]=w11; cv1.u[2]=w12; cv1.u[3]=w13;
            cv2.u[0]=w20; cv2.u[1]=w21; cv2.u[2]=w22; cv2.u[3]=w23;

            // layer 2 swapped: D[g=16nt2+g16*4+r][t=c16]
            float partial = 0.0f;
            #pragma unroll
            for (int nt2 = 0; nt2 < 3; ++nt2) {
                f32x4 c = { b2c[nt2][0], b2c[nt2][1], b2c[nt2][2], b2c[nt2][3] };
                c = __builtin_amdgcn_mfma_f32_16x16x32_bf16(bw[nt2][0], cv0.v, c, 0, 0, 0);
                c = __builtin_amdgcn_mfma_f32_16x16x32_bf16(bw[nt2][1], cv1.v, c, 0, 0, 0);
                c = __builtin_amdgcn_mfma_f32_16x16x32_bf16(bw[nt2][2], cv2.v, c, 0, 0, 0);
                partial += sigmoidf_(c[0]) * w3c[nt2][0];
                partial += sigmoidf_(c[1]) * w3c[nt2][1];
                partial += sigmoidf_(c[2]) * w3c[nt2][2];
                partial += sigmoidf_(c[3]) * w3c[nt2][3];
            }
            // reduce over the 4 g16 groups -> every lane holds score[t=c16]
            partial += __shfl_xor(partial, 16);
            partial += __shfl_xor(partial, 32);
            float sc = (partial + b3v) * 0.125f;
            if (sub == 0) sA = sc; else sB = sc;
        }

        // fixed-m softmax (scores bounded by weight norms; exp-safe)
        const int tb = pp * 32;
        float pA = (tb + c16 < mv)      ? __expf(sA) : 0.0f;
        float pB = (tb + 16 + c16 < mv) ? __expf(sB) : 0.0f;

        float psum = pA + pB;
        psum += __shfl_xor(psum, 1);
        psum += __shfl_xor(psum, 2);
        psum += __shfl_xor(psum, 4);
        psum += __shfl_xor(psum, 8);
        l_run += psum;

        o00 = fmaf(pB, (float)afB0[0], fmaf(pA, (float)afA0[0], o00));
        o01 = fmaf(pB, (float)afB0[1], fmaf(pA, (float)afA0[1], o01));
        o02 = fmaf(pB, (float)afB0[2], fmaf(pA, (float)afA0[2], o02));
        o03 = fmaf(pB, (float)afB0[3], fmaf(pA, (float)afA0[3], o03));
        o04 = fmaf(pB, (float)afB0[4], fmaf(pA, (float)afA0[4], o04));
        o05 = fmaf(pB, (float)afB0[5], fmaf(pA, (float)afA0[5], o05));
        o06 = fmaf(pB, (float)afB0[6], fmaf(pA, (float)afA0[6], o06));
        o07 = fmaf(pB, (float)afB0[7], fmaf(pA, (float)afA0[7], o07));
        o08 = fmaf(pB, (float)afB1[0], fmaf(pA, (float)afA1[0], o08));
        o09 = fmaf(pB, (float)afB1[1], fmaf(pA, (float)afA1[1], o09));
        o10 = fmaf(pB, (float)afB1[2], fmaf(pA, (float)afA1[2], o10));
        o11 = fmaf(pB, (float)afB1[3], fmaf(pA, (float)afA1[3], o11));
        o12 = fmaf(pB, (float)afB1[4], fmaf(pA, (float)afA1[4], o12));
        o13 = fmaf(pB, (float)afB1[5], fmaf(pA, (float)afA1[5], o13));
        o14 = fmaf(pB, (float)afB1[6], fmaf(pA, (float)afA1[6], o14));
        o15 = fmaf(pB, (float)afB1[7], fmaf(pA, (float)afA1[7], o15));
    }

    // ---------------- finalize: reduce o over c16 lanes, normalize, store ----------------
    #define ORED(X) X += __shfl_xor(X,1); X += __shfl_xor(X,2); X += __shfl_xor(X,4); X += __shfl_xor(X,8);
    ORED(o00) ORED(o01) ORED(o02) ORED(o03) ORED(o04) ORED(o05) ORED(o06) ORED(o07)
    ORED(o08) ORED(o09) ORED(o10) ORED(o11) ORED(o12) ORED(o13) ORED(o14) ORED(o15)
    #undef ORED
    float inv_total = __builtin_amdgcn_rcpf(l_run);
    if (c16 == 0) {
        float* sp = &s_part[w][0];
        sp[g16 * 8 + 0] = o00;  sp[g16 * 8 + 1] = o01;
        sp[g16 * 8 + 2] = o02;  sp[g16 * 8 + 3] = o03;
        sp[g16 * 8 + 4] = o04;  sp[g16 * 8 + 5] = o05;
        sp[g16 * 8 + 6] = o06;  sp[g16 * 8 + 7] = o07;
        sp[32 + g16 * 8 + 0] = o08;  sp[32 + g16 * 8 + 1] = o09;
        sp[32 + g16 * 8 + 2] = o10;  sp[32 + g16 * 8 + 3] = o11;
        sp[32 + g16 * 8 + 4] = o12;  sp[32 + g16 * 8 + 5] = o13;
        sp[32 + g16 * 8 + 6] = o14;  sp[32 + g16 * 8 + 7] = o15;
    }
    asm volatile("s_waitcnt lgkmcnt(0)" ::: "memory");
    out[b * D_ + lane] = s_part[w][lane] * inv_total;
}

extern "C" void kernel_launch(void* const* d_in, const int* in_sizes, int n_in,
                              void* d_out, int out_size, void* d_ws, size_t ws_size,
                              hipStream_t stream)
{
    const float* query = (const float*)d_in[0];
    const float* key   = (const float*)d_in[1];
    const int*   mask  = (const int*)  d_in[2];
    const float* W1    = (const float*)d_in[3];
    const float* b1    = (const float*)d_in[4];
    const float* W2    = (const float*)d_in[5];
    const float* b2    = (const float*)d_in[6];
    const float* W3    = (const float*)d_in[7];
    const float* b3    = (const float*)d_in[8];
    float* out = (float*)d_out;

    prep_kernel<<<8, 256, 0, stream>>>(W1, W2, d_ws);
    attn_din18<<<512, 256, 0, stream>>>(query, key, mask, b1, b2, W3, b3, d_ws, out);
}

// Round 19
// 42.639 us; speedup vs baseline: 1.6478x; 1.0259x over previous
//
#include <hip/hip_runtime.h>
#include <math.h>

#define B_  2048
#define T_  200
#define D_  64
#define H1_ 80
#define H2_ 40

#define WSTR 104   // ws W2T row stride (bf16)

// d_ws layout (bytes):
#define WS_A    0        // A[h][f]  bf16 [80][64]
#define WS_C    10240    // C[h][f]  bf16 [80][64]
#define WS_W2T  20480    // W2Tp[g][h] bf16 [48][104]
#define WS_ACT  30464    // W1acT[h][f] f32 [80][64]

typedef __bf16 bf16x8 __attribute__((ext_vector_type(8)));
typedef float  f32x4  __attribute__((ext_vector_type(4)));

__device__ __forceinline__ float sigmoidf_(float x) {
    return __builtin_amdgcn_rcpf(1.0f + __expf(-x));
}
__device__ __forceinline__ unsigned pk2_(float a, float b) {
    __bf16 x = (__bf16)a, y = (__bf16)b;
    unsigned short ux = __builtin_bit_cast(unsigned short, x);
    unsigned short uy = __builtin_bit_cast(unsigned short, y);
    return (unsigned)ux | ((unsigned)uy << 16);
}

// ---------- prep: block-invariant weight transforms ----------
__global__ __launch_bounds__(256)
void prep_kernel(const float* __restrict__ W1, const float* __restrict__ W2,
                 void* __restrict__ ws)
{
    __bf16* A    = (__bf16*)((char*)ws + WS_A);
    __bf16* C    = (__bf16*)((char*)ws + WS_C);
    __bf16* W2Tp = (__bf16*)((char*)ws + WS_W2T);
    float*  acT  = (float*)((char*)ws + WS_ACT);
    const int e0 = blockIdx.x * 256 + threadIdx.x;

    for (int e = e0; e < H1_ * D_; e += 2048) {
        int h = e >> 6, f = e & 63;
        float wb = W1[(64  + f) * H1_ + h];
        float wc = W1[(128 + f) * H1_ + h];
        float wd = W1[(192 + f) * H1_ + h];
        float wa = W1[f * H1_ + h];
        A[e]   = (__bf16)(wb - wc);
        C[e]   = (__bf16)wd;
        acT[e] = wa + wc;
    }
    for (int e = e0; e < 48 * WSTR; e += 2048) {
        int g = e / WSTR, h = e - g * WSTR;
        W2Tp[e] = (g < H2_ && h < H1_) ? (__bf16)W2[h * H2_ + g] : (__bf16)0.0f;
    }
}

// ---------- main: one batch per wave, swapped-operand MFMAs, LDS-free main loop ----------
__global__ __launch_bounds__(256, 2)
void attn_din19(const float* __restrict__ query,
                const float* __restrict__ key,
                const int*   __restrict__ mask,
                const float* __restrict__ b1,
                const float* __restrict__ b2,
                const float* __restrict__ W3,
                const float* __restrict__ b3,
                const void*  __restrict__ ws,
                float* __restrict__ out)
{
    __shared__ __align__(16) float s_q[4][D_];
    __shared__ float s_base[4][H1_];
    __shared__ float s_part[4][D_];
    // ~3.3 KB

    const int tid  = threadIdx.x;
    const int lane = tid & 63;
    const int w    = tid >> 6;
    const int c16  = lane & 15;
    const int g16  = lane >> 4;
    const int b    = blockIdx.x * 4 + w;

    const int   mv     = mask[b];
    const int   npairs = (mv + 31) >> 5;
    const float b3s    = b3[0] * 0.125f;      // folded score scale
    const float* kb = key + (size_t)b * T_ * D_;

    const __bf16* wsA   = (const __bf16*)((const char*)ws + WS_A);
    const __bf16* wsC   = (const __bf16*)((const char*)ws + WS_C);
    const __bf16* wsW2T = (const __bf16*)((const char*)ws + WS_W2T);
    const float*  wsacT = (const float*) ((const char*)ws + WS_ACT);

    // ---- q + pair-0 key loads issued early ----
    float qv = query[b * D_ + lane];
    float4 uA0, uA1, uA2, uA3, uB0, uB1, uB2, uB3;
    {
        const float* krA = kb + (size_t)c16 * D_ + g16 * 8;
        const float* krB = kb + (size_t)(16 + c16) * D_ + g16 * 8;
        uA0 = *(const float4*)(krA);      uA1 = *(const float4*)(krA + 4);
        uA2 = *(const float4*)(krA + 32); uA3 = *(const float4*)(krA + 36);
        uB0 = *(const float4*)(krB);      uB1 = *(const float4*)(krB + 4);
        uB2 = *(const float4*)(krB + 32); uB3 = *(const float4*)(krB + 36);
    }
    s_q[w][lane] = qv;

    // ---- W2T A-fragments ----
    bf16x8 bw[3][3];
    #pragma unroll
    for (int nt = 0; nt < 3; ++nt)
        #pragma unroll
        for (int ks = 0; ks < 3; ++ks)
            bw[nt][ks] = *(const bf16x8*)&wsW2T[(nt * 16 + c16) * WSTR + ks * 32 + g16 * 8];

    // ---- per-lane bias/weight rows for swapped outputs (scale folded into w3) ----
    float b2c[3][4], w3c[3][4];
    #pragma unroll
    for (int nt = 0; nt < 3; ++nt)
        #pragma unroll
        for (int r = 0; r < 4; ++r) {
            int g = nt * 16 + g16 * 4 + r;
            b2c[nt][r] = (g < H2_) ? b2[g] : 0.0f;
            w3c[nt][r] = (g < H2_) ? W3[g] * 0.125f : 0.0f;
        }

    // ---- base[h] into LDS ----
    {
        float a0 = b1[lane], a1 = 0.0f, a2 = 0.0f, a3 = 0.0f;
        const f32x4* row = (const f32x4*)&wsacT[lane * D_];
        #pragma unroll
        for (int f4 = 0; f4 < 16; ++f4) {
            f32x4 v  = row[f4];
            f32x4 q4 = *(const f32x4*)&s_q[w][f4 * 4];
            a0 = fmaf(q4[0], v[0], a0);
            a1 = fmaf(q4[1], v[1], a1);
            a2 = fmaf(q4[2], v[2], a2);
            a3 = fmaf(q4[3], v[3], a3);
        }
        s_base[w][lane] = (a0 + a1) + (a2 + a3);
    }
    if (lane < 16) {
        int h = 64 + lane;
        float a0 = b1[h], a1 = 0.0f, a2 = 0.0f, a3 = 0.0f;
        const f32x4* row = (const f32x4*)&wsacT[h * D_];
        #pragma unroll
        for (int f4 = 0; f4 < 16; ++f4) {
            f32x4 v  = row[f4];
            f32x4 q4 = *(const f32x4*)&s_q[w][f4 * 4];
            a0 = fmaf(q4[0], v[0], a0);
            a1 = fmaf(q4[1], v[1], a1);
            a2 = fmaf(q4[2], v[2], a2);
            a3 = fmaf(q4[3], v[3], a3);
        }
        s_base[w][h] = (a0 + a1) + (a2 + a3);
    }

    // ---- V A-fragments ----
    bf16x8 bv[5][2];
    #pragma unroll
    for (int mt = 0; mt < 5; ++mt)
        #pragma unroll
        for (int ks = 0; ks < 2; ++ks) {
            int off = (mt * 16 + c16) * D_ + ks * 32 + g16 * 8;
            bf16x8 a8 = *(const bf16x8*)&wsA[off];
            bf16x8 c8 = *(const bf16x8*)&wsC[off];
            f32x4 q0 = *(const f32x4*)&s_q[w][ks * 32 + g16 * 8];
            f32x4 q1 = *(const f32x4*)&s_q[w][ks * 32 + g16 * 8 + 4];
            bf16x8 v8;
            v8[0] = (__bf16)((float)a8[0] + q0[0] * (float)c8[0]);
            v8[1] = (__bf16)((float)a8[1] + q0[1] * (float)c8[1]);
            v8[2] = (__bf16)((float)a8[2] + q0[2] * (float)c8[2]);
            v8[3] = (__bf16)((float)a8[3] + q0[3] * (float)c8[3]);
            v8[4] = (__bf16)((float)a8[4] + q1[0] * (float)c8[4]);
            v8[5] = (__bf16)((float)a8[5] + q1[1] * (float)c8[5]);
            v8[6] = (__bf16)((float)a8[6] + q1[2] * (float)c8[6]);
            v8[7] = (__bf16)((float)a8[7] + q1[3] * (float)c8[7]);
            bv[mt][ks] = v8;
        }

    // ---- per-lane base rows: h = 16*mt + g16*4 + r ----
    float base_c[5][4];
    #pragma unroll
    for (int mt = 0; mt < 5; ++mt)
        #pragma unroll
        for (int r = 0; r < 4; ++r)
            base_c[mt][r] = s_base[w][16 * mt + g16 * 4 + r];

    // ---- shfl-assembly constants ----
    const int  L0 = ((g16 & 1) << 5) + c16;
    const int  L1 = L0 + 16;
    const bool hi = (g16 >= 2);

    // ---- accumulators (fixed-m softmax; l reduced only at the end) ----
    float o00,o01,o02,o03,o04,o05,o06,o07,o08,o09,o10,o11,o12,o13,o14,o15;
    o00=o01=o02=o03=o04=o05=o06=o07=o08=o09=o10=o11=o12=o13=o14=o15=0.0f;
    float l_run = 0.0f;

    // ---------------- main loop: 32 rows per iteration, LDS-free ----------------
    for (int pp = 0; pp < npairs; ++pp) {
        bf16x8 afA0, afA1, afB0, afB1;
        afA0[0]=(__bf16)uA0.x; afA0[1]=(__bf16)uA0.y; afA0[2]=(__bf16)uA0.z; afA0[3]=(__bf16)uA0.w;
        afA0[4]=(__bf16)uA1.x; afA0[5]=(__bf16)uA1.y; afA0[6]=(__bf16)uA1.z; afA0[7]=(__bf16)uA1.w;
        afA1[0]=(__bf16)uA2.x; afA1[1]=(__bf16)uA2.y; afA1[2]=(__bf16)uA2.z; afA1[3]=(__bf16)uA2.w;
        afA1[4]=(__bf16)uA3.x; afA1[5]=(__bf16)uA3.y; afA1[6]=(__bf16)uA3.z; afA1[7]=(__bf16)uA3.w;
        afB0[0]=(__bf16)uB0.x; afB0[1]=(__bf16)uB0.y; afB0[2]=(__bf16)uB0.z; afB0[3]=(__bf16)uB0.w;
        afB0[4]=(__bf16)uB1.x; afB0[5]=(__bf16)uB1.y; afB0[6]=(__bf16)uB1.z; afB0[7]=(__bf16)uB1.w;
        afB1[0]=(__bf16)uB2.x; afB1[1]=(__bf16)uB2.y; afB1[2]=(__bf16)uB2.z; afB1[3]=(__bf16)uB2.w;
        afB1[4]=(__bf16)uB3.x; afB1[5]=(__bf16)uB3.y; afB1[6]=(__bf16)uB3.z; afB1[7]=(__bf16)uB3.w;

        // T14 prefetch next pair
        if (pp + 1 < npairs) {
            int trA = (pp + 1) * 32 + c16;
            int trB = trA + 16;
            const float* krA = kb + (size_t)((trA < T_) ? trA : (T_ - 1)) * D_ + g16 * 8;
            const float* krB = kb + (size_t)((trB < T_) ? trB : (T_ - 1)) * D_ + g16 * 8;
            uA0 = *(const float4*)(krA);      uA1 = *(const float4*)(krA + 4);
            uA2 = *(const float4*)(krA + 32); uA3 = *(const float4*)(krA + 36);
            uB0 = *(const float4*)(krB);      uB1 = *(const float4*)(krB + 4);
            uB2 = *(const float4*)(krB + 32); uB3 = *(const float4*)(krB + 36);
        }

        // layer 1 swapped: D[h=16mt+g16*4+r][t=c16]; sigmoid -> packed bf16 pairs
        unsigned pkA[5][2], pkB[5][2];
        __builtin_amdgcn_s_setprio(1);
        #pragma unroll
        for (int mt = 0; mt < 5; ++mt) {
            f32x4 cA = { base_c[mt][0], base_c[mt][1], base_c[mt][2], base_c[mt][3] };
            cA = __builtin_amdgcn_mfma_f32_16x16x32_bf16(bv[mt][0], afA0, cA, 0, 0, 0);
            cA = __builtin_amdgcn_mfma_f32_16x16x32_bf16(bv[mt][1], afA1, cA, 0, 0, 0);
            f32x4 cB = { base_c[mt][0], base_c[mt][1], base_c[mt][2], base_c[mt][3] };
            cB = __builtin_amdgcn_mfma_f32_16x16x32_bf16(bv[mt][0], afB0, cB, 0, 0, 0);
            cB = __builtin_amdgcn_mfma_f32_16x16x32_bf16(bv[mt][1], afB1, cB, 0, 0, 0);
            pkA[mt][0] = pk2_(sigmoidf_(cA[0]), sigmoidf_(cA[1]));
            pkA[mt][1] = pk2_(sigmoidf_(cA[2]), sigmoidf_(cA[3]));
            pkB[mt][0] = pk2_(sigmoidf_(cB[0]), sigmoidf_(cB[1]));
            pkB[mt][1] = pk2_(sigmoidf_(cB[2]), sigmoidf_(cB[3]));
        }
        __builtin_amdgcn_s_setprio(0);

        // B-frag assembly + layer 2 + layer 3, per sub-tile
        float sA, sB;
        #pragma unroll
        for (int sub = 0; sub < 2; ++sub) {
            unsigned w00,w01,w02,w03, w10,w11,w12,w13, w20,w21,w22,w23;
            {
                #define PKX(m,i) (sub ? pkB[m][i] : pkA[m][i])
                unsigned a,bq;
                a = __shfl(PKX(0,0), L0); bq = __shfl(PKX(1,0), L0); w00 = hi ? bq : a;
                a = __shfl(PKX(0,1), L0); bq = __shfl(PKX(1,1), L0); w01 = hi ? bq : a;
                a = __shfl(PKX(0,0), L1); bq = __shfl(PKX(1,0), L1); w02 = hi ? bq : a;
                a = __shfl(PKX(0,1), L1); bq = __shfl(PKX(1,1), L1); w03 = hi ? bq : a;
                a = __shfl(PKX(2,0), L0); bq = __shfl(PKX(3,0), L0); w10 = hi ? bq : a;
                a = __shfl(PKX(2,1), L0); bq = __shfl(PKX(3,1), L0); w11 = hi ? bq : a;
                a = __shfl(PKX(2,0), L1); bq = __shfl(PKX(3,0), L1); w12 = hi ? bq : a;
                a = __shfl(PKX(2,1), L1); bq = __shfl(PKX(3,1), L1); w13 = hi ? bq : a;
                a = __shfl(PKX(4,0), L0);                            w20 = hi ? 0u : a;
                a = __shfl(PKX(4,1), L0);                            w21 = hi ? 0u : a;
                a = __shfl(PKX(4,0), L1);                            w22 = hi ? 0u : a;
                a = __shfl(PKX(4,1), L1);                            w23 = hi ? 0u : a;
                #undef PKX
            }
            union { unsigned u[4]; bf16x8 v; } cv0, cv1, cv2;
            cv0.u[0]=w00; cv0.u[1]=w01; cv0.u[2]=w02; cv0.u[3]=w03;
            cv1.u[0]=w10; cv1.u[1]=w11; cv1.u[2]=w12; cv1.u[3]=w13;
            cv2.u[0]=w20; cv2.u[1]=w21; cv2.u[2]=w22; cv2.u[3]=w23;

            // layer 2 swapped + layer 3 (w3 pre-scaled by 0.125)
            float partial = 0.0f;
            __builtin_amdgcn_s_setprio(1);
            #pragma unroll
            for (int nt2 = 0; nt2 < 3; ++nt2) {
                f32x4 c = { b2c[nt2][0], b2c[nt2][1], b2c[nt2][2], b2c[nt2][3] };
                c = __builtin_amdgcn_mfma_f32_16x16x32_bf16(bw[nt2][0], cv0.v, c, 0, 0, 0);
                c = __builtin_amdgcn_mfma_f32_16x16x32_bf16(bw[nt2][1], cv1.v, c, 0, 0, 0);
                c = __builtin_amdgcn_mfma_f32_16x16x32_bf16(bw[nt2][2], cv2.v, c, 0, 0, 0);
                partial += sigmoidf_(c[0]) * w3c[nt2][0];
                partial += sigmoidf_(c[1]) * w3c[nt2][1];
                partial += sigmoidf_(c[2]) * w3c[nt2][2];
                partial += sigmoidf_(c[3]) * w3c[nt2][3];
            }
            __builtin_amdgcn_s_setprio(0);
            partial += __shfl_xor(partial, 16);
            partial += __shfl_xor(partial, 32);
            float sc = partial + b3s;
            if (sub == 0) sA = sc; else sB = sc;
        }

        // fixed-m softmax; l accumulated per-lane (reduced once in finalize)
        const int tb = pp * 32;
        float pA = (tb + c16 < mv)      ? __expf(sA) : 0.0f;
        float pB = (tb + 16 + c16 < mv) ? __expf(sB) : 0.0f;
        l_run += pA + pB;

        o00 = fmaf(pB, (float)afB0[0], fmaf(pA, (float)afA0[0], o00));
        o01 = fmaf(pB, (float)afB0[1], fmaf(pA, (float)afA0[1], o01));
        o02 = fmaf(pB, (float)afB0[2], fmaf(pA, (float)afA0[2], o02));
        o03 = fmaf(pB, (float)afB0[3], fmaf(pA, (float)afA0[3], o03));
        o04 = fmaf(pB, (float)afB0[4], fmaf(pA, (float)afA0[4], o04));
        o05 = fmaf(pB, (float)afB0[5], fmaf(pA, (float)afA0[5], o05));
        o06 = fmaf(pB, (float)afB0[6], fmaf(pA, (float)afA0[6], o06));
        o07 = fmaf(pB, (float)afB0[7], fmaf(pA, (float)afA0[7], o07));
        o08 = fmaf(pB, (float)afB1[0], fmaf(pA, (float)afA1[0], o08));
        o09 = fmaf(pB, (float)afB1[1], fmaf(pA, (float)afA1[1], o09));
        o10 = fmaf(pB, (float)afB1[2], fmaf(pA, (float)afA1[2], o10));
        o11 = fmaf(pB, (float)afB1[3], fmaf(pA, (float)afA1[3], o11));
        o12 = fmaf(pB, (float)afB1[4], fmaf(pA, (float)afA1[4], o12));
        o13 = fmaf(pB, (float)afB1[5], fmaf(pA, (float)afA1[5], o13));
        o14 = fmaf(pB, (float)afB1[6], fmaf(pA, (float)afA1[6], o14));
        o15 = fmaf(pB, (float)afB1[7], fmaf(pA, (float)afA1[7], o15));
    }

    // ---------------- finalize: reduce o and l over c16 lanes, normalize, store ----------------
    #define ORED(X) X += __shfl_xor(X,1); X += __shfl_xor(X,2); X += __shfl_xor(X,4); X += __shfl_xor(X,8);
    ORED(o00) ORED(o01) ORED(o02) ORED(o03) ORED(o04) ORED(o05) ORED(o06) ORED(o07)
    ORED(o08) ORED(o09) ORED(o10) ORED(o11) ORED(o12) ORED(o13) ORED(o14) ORED(o15)
    ORED(l_run)
    #undef ORED
    float inv_total = __builtin_amdgcn_rcpf(l_run);
    if (c16 == 0) {
        float* sp = &s_part[w][0];
        sp[g16 * 8 + 0] = o00;  sp[g16 * 8 + 1] = o01;
        sp[g16 * 8 + 2] = o02;  sp[g16 * 8 + 3] = o03;
        sp[g16 * 8 + 4] = o04;  sp[g16 * 8 + 5] = o05;
        sp[g16 * 8 + 6] = o06;  sp[g16 * 8 + 7] = o07;
        sp[32 + g16 * 8 + 0] = o08;  sp[32 + g16 * 8 + 1] = o09;
        sp[32 + g16 * 8 + 2] = o10;  sp[32 + g16 * 8 + 3] = o11;
        sp[32 + g16 * 8 + 4] = o12;  sp[32 + g16 * 8 + 5] = o13;
        sp[32 + g16 * 8 + 6] = o14;  sp[32 + g16 * 8 + 7] = o15;
    }
    asm volatile("s_waitcnt lgkmcnt(0)" ::: "memory");
    out[b * D_ + lane] = s_part[w][lane] * inv_total;
}

extern "C" void kernel_launch(void* const* d_in, const int* in_sizes, int n_in,
                              void* d_out, int out_size, void* d_ws, size_t ws_size,
                              hipStream_t stream)
{
    const float* query = (const float*)d_in[0];
    const float* key   = (const float*)d_in[1];
    const int*   mask  = (const int*)  d_in[2];
    const float* W1    = (const float*)d_in[3];
    const float* b1    = (const float*)d_in[4];
    const float* W2    = (const float*)d_in[5];
    const float* b2    = (const float*)d_in[6];
    const float* W3    = (const float*)d_in[7];
    const float* b3    = (const float*)d_in[8];
    float* out = (float*)d_out;

    prep_kernel<<<8, 256, 0, stream>>>(W1, W2, d_ws);
    attn_din19<<<512, 256, 0, stream>>>(query, key, mask, b1, b2, W3, b3, d_ws, out);
}

// Round 20
// 41.645 us; speedup vs baseline: 1.6872x; 1.0239x over previous
//
#include <hip/hip_runtime.h>
#include <math.h>

#define B_  2048
#define T_  200
#define D_  64
#define H1_ 80
#define H2_ 40

#define WSTR 104   // ws W2T row stride (bf16)
#define NLOG2E (-1.4426950408889634f)
#define LOG2E  (1.4426950408889634f)

// d_ws layout (bytes):
#define WS_A    0        // A[h][f]  bf16 [80][64]   (pre-scaled by -log2e)
#define WS_C    10240    // C[h][f]  bf16 [80][64]   (pre-scaled by -log2e)
#define WS_W2T  20480    // W2Tp[g][h] bf16 [48][104] (pre-scaled by -log2e)
#define WS_ACT  30464    // W1acT[h][f] f32 [80][64]  (unscaled)

typedef __bf16 bf16x8 __attribute__((ext_vector_type(8)));
typedef float  f32x4  __attribute__((ext_vector_type(4)));

// y is already -log2e * x : sigmoid(x) = 1 / (1 + 2^y)
__device__ __forceinline__ float sigmoid2_(float y) {
    return __builtin_amdgcn_rcpf(1.0f + __builtin_amdgcn_exp2f(y));
}
__device__ __forceinline__ unsigned pk2_(float a, float b) {
    __bf16 x = (__bf16)a, y = (__bf16)b;
    unsigned short ux = __builtin_bit_cast(unsigned short, x);
    unsigned short uy = __builtin_bit_cast(unsigned short, y);
    return (unsigned)ux | ((unsigned)uy << 16);
}

// ---------- prep: block-invariant weight transforms (exp2-folded) ----------
__global__ __launch_bounds__(256)
void prep_kernel(const float* __restrict__ W1, const float* __restrict__ W2,
                 void* __restrict__ ws)
{
    __bf16* A    = (__bf16*)((char*)ws + WS_A);
    __bf16* C    = (__bf16*)((char*)ws + WS_C);
    __bf16* W2Tp = (__bf16*)((char*)ws + WS_W2T);
    float*  acT  = (float*)((char*)ws + WS_ACT);
    const int e0 = blockIdx.x * 256 + threadIdx.x;

    for (int e = e0; e < H1_ * D_; e += 2048) {
        int h = e >> 6, f = e & 63;
        float wb = W1[(64  + f) * H1_ + h];
        float wc = W1[(128 + f) * H1_ + h];
        float wd = W1[(192 + f) * H1_ + h];
        float wa = W1[f * H1_ + h];
        A[e]   = (__bf16)(NLOG2E * (wb - wc));
        C[e]   = (__bf16)(NLOG2E * wd);
        acT[e] = wa + wc;
    }
    for (int e = e0; e < 48 * WSTR; e += 2048) {
        int g = e / WSTR, h = e - g * WSTR;
        W2Tp[e] = (g < H2_ && h < H1_) ? (__bf16)(NLOG2E * W2[h * H2_ + g]) : (__bf16)0.0f;
    }
}

// ---------- main: one batch per wave, swapped-operand MFMAs, LDS-free main loop ----------
__global__ __launch_bounds__(256, 2)
void attn_din20(const float* __restrict__ query,
                const float* __restrict__ key,
                const int*   __restrict__ mask,
                const float* __restrict__ b1,
                const float* __restrict__ b2,
                const float* __restrict__ W3,
                const float* __restrict__ b3,
                const void*  __restrict__ ws,
                float* __restrict__ out)
{
    __shared__ __align__(16) float s_q[4][D_];
    __shared__ float s_base[4][H1_];
    __shared__ float s_part[4][D_];
    // ~3.3 KB

    const int tid  = threadIdx.x;
    const int lane = tid & 63;
    const int w    = tid >> 6;
    const int c16  = lane & 15;
    const int g16  = lane >> 4;
    const int b    = blockIdx.x * 4 + w;

    const int   mv     = mask[b];
    const int   npairs = (mv + 31) >> 5;
    const float b3s    = b3[0] * 0.125f * LOG2E;   // folded scale + log2e
    const float* kb = key + (size_t)b * T_ * D_;

    const __bf16* wsA   = (const __bf16*)((const char*)ws + WS_A);
    const __bf16* wsC   = (const __bf16*)((const char*)ws + WS_C);
    const __bf16* wsW2T = (const __bf16*)((const char*)ws + WS_W2T);
    const float*  wsacT = (const float*) ((const char*)ws + WS_ACT);

    // ---- q + pair-0 key loads issued early ----
    float qv = query[b * D_ + lane];
    float4 uA0, uA1, uA2, uA3, uB0, uB1, uB2, uB3;
    {
        const float* krA = kb + (size_t)c16 * D_ + g16 * 8;
        const float* krB = kb + (size_t)(16 + c16) * D_ + g16 * 8;
        uA0 = *(const float4*)(krA);      uA1 = *(const float4*)(krA + 4);
        uA2 = *(const float4*)(krA + 32); uA3 = *(const float4*)(krA + 36);
        uB0 = *(const float4*)(krB);      uB1 = *(const float4*)(krB + 4);
        uB2 = *(const float4*)(krB + 32); uB3 = *(const float4*)(krB + 36);
    }
    s_q[w][lane] = qv;

    // ---- W2T A-fragments (pre-scaled by -log2e in prep) ----
    bf16x8 bw[3][3];
    #pragma unroll
    for (int nt = 0; nt < 3; ++nt)
        #pragma unroll
        for (int ks = 0; ks < 3; ++ks)
            bw[nt][ks] = *(const bf16x8*)&wsW2T[(nt * 16 + c16) * WSTR + ks * 32 + g16 * 8];

    // ---- per-lane bias/weight rows (b2 scaled by -log2e; w3 by 0.125*log2e) ----
    float b2c[3][4], w3c[3][4];
    #pragma unroll
    for (int nt = 0; nt < 3; ++nt)
        #pragma unroll
        for (int r = 0; r < 4; ++r) {
            int g = nt * 16 + g16 * 4 + r;
            b2c[nt][r] = (g < H2_) ? b2[g] * NLOG2E : 0.0f;
            w3c[nt][r] = (g < H2_) ? W3[g] * 0.125f * LOG2E : 0.0f;
        }

    // ---- base[h] into LDS (unscaled) ----
    {
        float a0 = b1[lane], a1 = 0.0f, a2 = 0.0f, a3 = 0.0f;
        const f32x4* row = (const f32x4*)&wsacT[lane * D_];
        #pragma unroll
        for (int f4 = 0; f4 < 16; ++f4) {
            f32x4 v  = row[f4];
            f32x4 q4 = *(const f32x4*)&s_q[w][f4 * 4];
            a0 = fmaf(q4[0], v[0], a0);
            a1 = fmaf(q4[1], v[1], a1);
            a2 = fmaf(q4[2], v[2], a2);
            a3 = fmaf(q4[3], v[3], a3);
        }
        s_base[w][lane] = (a0 + a1) + (a2 + a3);
    }
    if (lane < 16) {
        int h = 64 + lane;
        float a0 = b1[h], a1 = 0.0f, a2 = 0.0f, a3 = 0.0f;
        const f32x4* row = (const f32x4*)&wsacT[h * D_];
        #pragma unroll
        for (int f4 = 0; f4 < 16; ++f4) {
            f32x4 v  = row[f4];
            f32x4 q4 = *(const f32x4*)&s_q[w][f4 * 4];
            a0 = fmaf(q4[0], v[0], a0);
            a1 = fmaf(q4[1], v[1], a1);
            a2 = fmaf(q4[2], v[2], a2);
            a3 = fmaf(q4[3], v[3], a3);
        }
        s_base[w][h] = (a0 + a1) + (a2 + a3);
    }

    // ---- V A-fragments (A,C pre-scaled by -log2e -> v8 arrives scaled) ----
    bf16x8 bv[5][2];
    #pragma unroll
    for (int mt = 0; mt < 5; ++mt)
        #pragma unroll
        for (int ks = 0; ks < 2; ++ks) {
            int off = (mt * 16 + c16) * D_ + ks * 32 + g16 * 8;
            bf16x8 a8 = *(const bf16x8*)&wsA[off];
            bf16x8 c8 = *(const bf16x8*)&wsC[off];
            f32x4 q0 = *(const f32x4*)&s_q[w][ks * 32 + g16 * 8];
            f32x4 q1 = *(const f32x4*)&s_q[w][ks * 32 + g16 * 8 + 4];
            bf16x8 v8;
            v8[0] = (__bf16)((float)a8[0] + q0[0] * (float)c8[0]);
            v8[1] = (__bf16)((float)a8[1] + q0[1] * (float)c8[1]);
            v8[2] = (__bf16)((float)a8[2] + q0[2] * (float)c8[2]);
            v8[3] = (__bf16)((float)a8[3] + q0[3] * (float)c8[3]);
            v8[4] = (__bf16)((float)a8[4] + q1[0] * (float)c8[4]);
            v8[5] = (__bf16)((float)a8[5] + q1[1] * (float)c8[5]);
            v8[6] = (__bf16)((float)a8[6] + q1[2] * (float)c8[6]);
            v8[7] = (__bf16)((float)a8[7] + q1[3] * (float)c8[7]);
            bv[mt][ks] = v8;
        }

    // ---- per-lane base rows, scaled by -log2e: h = 16*mt + g16*4 + r ----
    float base_c[5][4];
    #pragma unroll
    for (int mt = 0; mt < 5; ++mt)
        #pragma unroll
        for (int r = 0; r < 4; ++r)
            base_c[mt][r] = s_base[w][16 * mt + g16 * 4 + r] * NLOG2E;

    // ---- shfl-assembly constants ----
    const int  L0 = ((g16 & 1) << 5) + c16;
    const int  L1 = L0 + 16;
    const bool hi = (g16 >= 2);

    // ---- accumulators (fixed-m softmax; l reduced only at the end) ----
    float o00,o01,o02,o03,o04,o05,o06,o07,o08,o09,o10,o11,o12,o13,o14,o15;
    o00=o01=o02=o03=o04=o05=o06=o07=o08=o09=o10=o11=o12=o13=o14=o15=0.0f;
    float l_run = 0.0f;

    // ---------------- main loop: 32 rows per iteration, LDS-free ----------------
    for (int pp = 0; pp < npairs; ++pp) {
        bf16x8 afA0, afA1, afB0, afB1;
        afA0[0]=(__bf16)uA0.x; afA0[1]=(__bf16)uA0.y; afA0[2]=(__bf16)uA0.z; afA0[3]=(__bf16)uA0.w;
        afA0[4]=(__bf16)uA1.x; afA0[5]=(__bf16)uA1.y; afA0[6]=(__bf16)uA1.z; afA0[7]=(__bf16)uA1.w;
        afA1[0]=(__bf16)uA2.x; afA1[1]=(__bf16)uA2.y; afA1[2]=(__bf16)uA2.z; afA1[3]=(__bf16)uA2.w;
        afA1[4]=(__bf16)uA3.x; afA1[5]=(__bf16)uA3.y; afA1[6]=(__bf16)uA3.z; afA1[7]=(__bf16)uA3.w;
        afB0[0]=(__bf16)uB0.x; afB0[1]=(__bf16)uB0.y; afB0[2]=(__bf16)uB0.z; afB0[3]=(__bf16)uB0.w;
        afB0[4]=(__bf16)uB1.x; afB0[5]=(__bf16)uB1.y; afB0[6]=(__bf16)uB1.z; afB0[7]=(__bf16)uB1.w;
        afB1[0]=(__bf16)uB2.x; afB1[1]=(__bf16)uB2.y; afB1[2]=(__bf16)uB2.z; afB1[3]=(__bf16)uB2.w;
        afB1[4]=(__bf16)uB3.x; afB1[5]=(__bf16)uB3.y; afB1[6]=(__bf16)uB3.z; afB1[7]=(__bf16)uB3.w;

        // T14 prefetch next pair
        if (pp + 1 < npairs) {
            int trA = (pp + 1) * 32 + c16;
            int trB = trA + 16;
            const float* krA = kb + (size_t)((trA < T_) ? trA : (T_ - 1)) * D_ + g16 * 8;
            const float* krB = kb + (size_t)((trB < T_) ? trB : (T_ - 1)) * D_ + g16 * 8;
            uA0 = *(const float4*)(krA);      uA1 = *(const float4*)(krA + 4);
            uA2 = *(const float4*)(krA + 32); uA3 = *(const float4*)(krA + 36);
            uB0 = *(const float4*)(krB);      uB1 = *(const float4*)(krB + 4);
            uB2 = *(const float4*)(krB + 32); uB3 = *(const float4*)(krB + 36);
        }

        // layer 1 swapped (outputs pre-scaled by -log2e); sigmoid via exp2 -> packed bf16
        unsigned pkA[5][2], pkB[5][2];
        __builtin_amdgcn_s_setprio(1);
        #pragma unroll
        for (int mt = 0; mt < 5; ++mt) {
            f32x4 cA = { base_c[mt][0], base_c[mt][1], base_c[mt][2], base_c[mt][3] };
            cA = __builtin_amdgcn_mfma_f32_16x16x32_bf16(bv[mt][0], afA0, cA, 0, 0, 0);
            cA = __builtin_amdgcn_mfma_f32_16x16x32_bf16(bv[mt][1], afA1, cA, 0, 0, 0);
            f32x4 cB = { base_c[mt][0], base_c[mt][1], base_c[mt][2], base_c[mt][3] };
            cB = __builtin_amdgcn_mfma_f32_16x16x32_bf16(bv[mt][0], afB0, cB, 0, 0, 0);
            cB = __builtin_amdgcn_mfma_f32_16x16x32_bf16(bv[mt][1], afB1, cB, 0, 0, 0);
            pkA[mt][0] = pk2_(sigmoid2_(cA[0]), sigmoid2_(cA[1]));
            pkA[mt][1] = pk2_(sigmoid2_(cA[2]), sigmoid2_(cA[3]));
            pkB[mt][0] = pk2_(sigmoid2_(cB[0]), sigmoid2_(cB[1]));
            pkB[mt][1] = pk2_(sigmoid2_(cB[2]), sigmoid2_(cB[3]));
        }
        __builtin_amdgcn_s_setprio(0);

        // B-frag assembly + layer 2 + layer 3, per sub-tile
        float sA, sB;
        #pragma unroll
        for (int sub = 0; sub < 2; ++sub) {
            unsigned w00,w01,w02,w03, w10,w11,w12,w13, w20,w21,w22,w23;
            {
                #define PKX(m,i) (sub ? pkB[m][i] : pkA[m][i])
                unsigned a,bq;
                a = __shfl(PKX(0,0), L0); bq = __shfl(PKX(1,0), L0); w00 = hi ? bq : a;
                a = __shfl(PKX(0,1), L0); bq = __shfl(PKX(1,1), L0); w01 = hi ? bq : a;
                a = __shfl(PKX(0,0), L1); bq = __shfl(PKX(1,0), L1); w02 = hi ? bq : a;
                a = __shfl(PKX(0,1), L1); bq = __shfl(PKX(1,1), L1); w03 = hi ? bq : a;
                a = __shfl(PKX(2,0), L0); bq = __shfl(PKX(3,0), L0); w10 = hi ? bq : a;
                a = __shfl(PKX(2,1), L0); bq = __shfl(PKX(3,1), L0); w11 = hi ? bq : a;
                a = __shfl(PKX(2,0), L1); bq = __shfl(PKX(3,0), L1); w12 = hi ? bq : a;
                a = __shfl(PKX(2,1), L1); bq = __shfl(PKX(3,1), L1); w13 = hi ? bq : a;
                a = __shfl(PKX(4,0), L0);                            w20 = hi ? 0u : a;
                a = __shfl(PKX(4,1), L0);                            w21 = hi ? 0u : a;
                a = __shfl(PKX(4,0), L1);                            w22 = hi ? 0u : a;
                a = __shfl(PKX(4,1), L1);                            w23 = hi ? 0u : a;
                #undef PKX
            }
            union { unsigned u[4]; bf16x8 v; } cv0, cv1, cv2;
            cv0.u[0]=w00; cv0.u[1]=w01; cv0.u[2]=w02; cv0.u[3]=w03;
            cv1.u[0]=w10; cv1.u[1]=w11; cv1.u[2]=w12; cv1.u[3]=w13;
            cv2.u[0]=w20; cv2.u[1]=w21; cv2.u[2]=w22; cv2.u[3]=w23;

            // layer 2 swapped (outputs pre-scaled by -log2e) + layer 3 (tree)
            float p0 = 0.0f, p1 = 0.0f, p2 = 0.0f, p3 = 0.0f;
            __builtin_amdgcn_s_setprio(1);
            #pragma unroll
            for (int nt2 = 0; nt2 < 3; ++nt2) {
                f32x4 c = { b2c[nt2][0], b2c[nt2][1], b2c[nt2][2], b2c[nt2][3] };
                c = __builtin_amdgcn_mfma_f32_16x16x32_bf16(bw[nt2][0], cv0.v, c, 0, 0, 0);
                c = __builtin_amdgcn_mfma_f32_16x16x32_bf16(bw[nt2][1], cv1.v, c, 0, 0, 0);
                c = __builtin_amdgcn_mfma_f32_16x16x32_bf16(bw[nt2][2], cv2.v, c, 0, 0, 0);
                p0 = fmaf(sigmoid2_(c[0]), w3c[nt2][0], p0);
                p1 = fmaf(sigmoid2_(c[1]), w3c[nt2][1], p1);
                p2 = fmaf(sigmoid2_(c[2]), w3c[nt2][2], p2);
                p3 = fmaf(sigmoid2_(c[3]), w3c[nt2][3], p3);
            }
            __builtin_amdgcn_s_setprio(0);
            float partial = (p0 + p1) + (p2 + p3);
            partial += __shfl_xor(partial, 16);
            partial += __shfl_xor(partial, 32);
            float sc = partial + b3s;          // sc is log2-domain score
            if (sub == 0) sA = sc; else sB = sc;
        }

        // fixed-m softmax in exp2 domain; l accumulated per-lane
        const int tb = pp * 32;
        float pA = (tb + c16 < mv)      ? __builtin_amdgcn_exp2f(sA) : 0.0f;
        float pB = (tb + 16 + c16 < mv) ? __builtin_amdgcn_exp2f(sB) : 0.0f;
        l_run += pA + pB;

        o00 = fmaf(pB, (float)afB0[0], fmaf(pA, (float)afA0[0], o00));
        o01 = fmaf(pB, (float)afB0[1], fmaf(pA, (float)afA0[1], o01));
        o02 = fmaf(pB, (float)afB0[2], fmaf(pA, (float)afA0[2], o02));
        o03 = fmaf(pB, (float)afB0[3], fmaf(pA, (float)afA0[3], o03));
        o04 = fmaf(pB, (float)afB0[4], fmaf(pA, (float)afA0[4], o04));
        o05 = fmaf(pB, (float)afB0[5], fmaf(pA, (float)afA0[5], o05));
        o06 = fmaf(pB, (float)afB0[6], fmaf(pA, (float)afA0[6], o06));
        o07 = fmaf(pB, (float)afB0[7], fmaf(pA, (float)afA0[7], o07));
        o08 = fmaf(pB, (float)afB1[0], fmaf(pA, (float)afA1[0], o08));
        o09 = fmaf(pB, (float)afB1[1], fmaf(pA, (float)afA1[1], o09));
        o10 = fmaf(pB, (float)afB1[2], fmaf(pA, (float)afA1[2], o10));
        o11 = fmaf(pB, (float)afB1[3], fmaf(pA, (float)afA1[3], o11));
        o12 = fmaf(pB, (float)afB1[4], fmaf(pA, (float)afA1[4], o12));
        o13 = fmaf(pB, (float)afB1[5], fmaf(pA, (float)afA1[5], o13));
        o14 = fmaf(pB, (float)afB1[6], fmaf(pA, (float)afA1[6], o14));
        o15 = fmaf(pB, (float)afB1[7], fmaf(pA, (float)afA1[7], o15));
    }

    // ---------------- finalize: reduce o and l over c16 lanes, normalize, store ----------------
    #define ORED(X) X += __shfl_xor(X,1); X += __shfl_xor(X,2); X += __shfl_xor(X,4); X += __shfl_xor(X,8);
    ORED(o00) ORED(o01) ORED(o02) ORED(o03) ORED(o04) ORED(o05) ORED(o06) ORED(o07)
    ORED(o08) ORED(o09) ORED(o10) ORED(o11) ORED(o12) ORED(o13) ORED(o14) ORED(o15)
    ORED(l_run)
    #undef ORED
    float inv_total = __builtin_amdgcn_rcpf(l_run);
    if (c16 == 0) {
        float* sp = &s_part[w][0];
        sp[g16 * 8 + 0] = o00;  sp[g16 * 8 + 1] = o01;
        sp[g16 * 8 + 2] = o02;  sp[g16 * 8 + 3] = o03;
        sp[g16 * 8 + 4] = o04;  sp[g16 * 8 + 5] = o05;
        sp[g16 * 8 + 6] = o06;  sp[g16 * 8 + 7] = o07;
        sp[32 + g16 * 8 + 0] = o08;  sp[32 + g16 * 8 + 1] = o09;
        sp[32 + g16 * 8 + 2] = o10;  sp[32 + g16 * 8 + 3] = o11;
        sp[32 + g16 * 8 + 4] = o12;  sp[32 + g16 * 8 + 5] = o13;
        sp[32 + g16 * 8 + 6] = o14;  sp[32 + g16 * 8 + 7] = o15;
    }
    asm volatile("s_waitcnt lgkmcnt(0)" ::: "memory");
    out[b * D_ + lane] = s_part[w][lane] * inv_total;
}

extern "C" void kernel_launch(void* const* d_in, const int* in_sizes, int n_in,
                              void* d_out, int out_size, void* d_ws, size_t ws_size,
                              hipStream_t stream)
{
    const float* query = (const float*)d_in[0];
    const float* key   = (const float*)d_in[1];
    const int*   mask  = (const int*)  d_in[2];
    const float* W1    = (const float*)d_in[3];
    const float* b1    = (const float*)d_in[4];
    const float* W2    = (const float*)d_in[5];
    const float* b2    = (const float*)d_in[6];
    const float* W3    = (const float*)d_in[7];
    const float* b3    = (const float*)d_in[8];
    float* out = (float*)d_out;

    prep_kernel<<<8, 256, 0, stream>>>(W1, W2, d_ws);
    attn_din20<<<512, 256, 0, stream>>>(query, key, mask, b1, b2, W3, b3, d_ws, out);
}